// Round 10
// baseline (211.313 us; speedup 1.0000x reference)
//
#include <hip/hip_runtime.h>
#include <cstddef>

typedef short short8 __attribute__((ext_vector_type(8)));
typedef unsigned short ushort8 __attribute__((ext_vector_type(8)));
typedef float f32x4 __attribute__((ext_vector_type(4)));

#define AS1(p) ((const __attribute__((address_space(1))) void*)(p))
#define AS3(p) ((__attribute__((address_space(3))) void*)(p))

__device__ __forceinline__ unsigned short f2bf(float f) {
  unsigned int u = __builtin_bit_cast(unsigned int, f);
  u += 0x7FFFu + ((u >> 16) & 1u);   // round-to-nearest-even
  return (unsigned short)(u >> 16);
}

__device__ __forceinline__ void gload_lds16(const void* g, void* l) {
  __builtin_amdgcn_global_load_lds(AS1(g), AS3(l), 16, 0, 0);
}

template <int N>
__device__ __forceinline__ void vwait() {
  asm volatile("s_waitcnt vmcnt(%0)" :: "n"(N) : "memory");
}

// ---------------------------------------------------------------------------
// Fused prep (ONE dispatch): W1 transpose+cvt, W2 transpose+cvt, X f32->bf16.
// blocks [0,4096): W1 -> W1t ; [4096,8192): W2 -> W2t ; [8192,16384): X cvt.
// ---------------------------------------------------------------------------
__global__ __launch_bounds__(256)
void prep_fused(const float* __restrict__ X,
                const float* __restrict__ W1,
                const float* __restrict__ W2,
                unsigned short* __restrict__ Xbf,
                unsigned short* __restrict__ W1t,
                unsigned short* __restrict__ W2t) {
  const int b   = blockIdx.x;
  const int tid = threadIdx.x;

  if (b >= 8192) {   // ---- X cvt: float4 in, 4x bf16 out ----
    const size_t i = (size_t)(b - 8192) * 256 + tid;   // 0 .. 2^21-1
    float4 v = *reinterpret_cast<const float4*>(X + i * 4);
    ushort4 o;
    o.x = f2bf(v.x); o.y = f2bf(v.y); o.z = f2bf(v.z); o.w = f2bf(v.w);
    *reinterpret_cast<ushort4*>(Xbf + i * 4) = o;
    return;
  }

  __shared__ float tile[32][33];
  const float* in;
  unsigned short* out;
  int Kd, Nd, n0, k0;
  if (b < 4096) {              // W1: Kd=1024 (H), Nd=4096 (I)
    in = W1; out = W1t; Kd = 1024; Nd = 4096;
    n0 = (b & 127) * 32;
    k0 = (b >> 7) * 32;
  } else {                     // W2: Kd=4096 (I), Nd=1024 (H)
    const int b2 = b - 4096;
    in = W2; out = W2t; Kd = 4096; Nd = 1024;
    n0 = (b2 & 31) * 32;
    k0 = (b2 >> 5) * 32;
  }
  const int tx = tid & 31;
  const int ty = tid >> 5;
#pragma unroll
  for (int i = 0; i < 4; ++i)
    tile[ty + i * 8][tx] = in[(size_t)(k0 + ty + i * 8) * Nd + n0 + tx];
  __syncthreads();
#pragma unroll
  for (int i = 0; i < 4; ++i)
    out[(size_t)(n0 + ty + i * 8) * Kd + k0 + tx] = f2bf(tile[tx][ty + i * 8]);
}

// ---------------------------------------------------------------------------
// Standalone prep kernels (fallback path only).
// ---------------------------------------------------------------------------
__global__ void cvt_f32_bf16(const float* __restrict__ in,
                             unsigned short* __restrict__ out, int n4) {
  int i = blockIdx.x * blockDim.x + threadIdx.x;
  if (i >= n4) return;
  float4 v = *reinterpret_cast<const float4*>(in + (size_t)i * 4);
  ushort4 o;
  o.x = f2bf(v.x); o.y = f2bf(v.y); o.z = f2bf(v.z); o.w = f2bf(v.w);
  *reinterpret_cast<ushort4*>(out + (size_t)i * 4) = o;
}

__global__ void transpose_cvt(const float* __restrict__ in,
                              unsigned short* __restrict__ out,
                              int Kd, int Nd) {
  __shared__ float tile[32][33];
  const int n0 = blockIdx.x * 32;
  const int k0 = blockIdx.y * 32;
  const int tx = threadIdx.x;
  const int ty = threadIdx.y;
#pragma unroll
  for (int i = 0; i < 4; ++i)
    tile[ty + i * 8][tx] = in[(size_t)(k0 + ty + i * 8) * Nd + n0 + tx];
  __syncthreads();
#pragma unroll
  for (int i = 0; i < 4; ++i)
    out[(size_t)(n0 + ty + i * 8) * Kd + k0 + tx] = f2bf(tile[tx][ty + i * 8]);
}

// ---------------------------------------------------------------------------
// BIG-WAVE GEMM (round-10 lever): 256x256 block, FOUR waves, per-wave tile
// 128x128 (8x8 16x16x32 frags, acc = 256 VGPR). Reads/MFMA drops 0.375 ->
// 0.25 (the LDS-amplification floor identified from rounds 2-9: all
// schedules pinned at 31% MfmaUtil because LDS fragment reads cost ~2.4-3.7x
// the MFMA time; this cuts the binding resource 33%).
// BK=64 double-buffered (128 KiB LDS): stage(next) -> vmcnt(16) counted
// (cur's loads done, next's 16 stay in flight) -> barrier -> compute ->
// barrier. Swizzle a^=((a>>7)&7)<<4 both sides (rule #21; measured-0-conflict
// pattern). __launch_bounds__(256,1): 512-VGPR budget, 1 wave/SIMD.
// ---------------------------------------------------------------------------
template <int RELU_BF16_OUT>
__global__ __launch_bounds__(256, 1)
void gemm_bw(const unsigned short* __restrict__ A, int lda,
             const unsigned short* __restrict__ B, int ldb,
             const float* __restrict__ bias,
             void* __restrict__ C, int ldc, int K, int nbx) {
  extern __shared__ char lds[];

  const int tid  = threadIdx.x;
  const int lane = tid & 63;
  const int wid  = tid >> 6;   // 0..3
  const int wm   = wid >> 1;
  const int wn   = wid & 1;

  // bijective XCD-chunked swizzle (grid % 8 == 0)
  const int cpx     = gridDim.x >> 3;
  const int logical = (blockIdx.x & 7) * cpx + (blockIdx.x >> 3);
  const int m0 = (logical / nbx) * 256;
  const int n0 = (logical % nbx) * 256;

  f32x4 acc[8][8];
#pragma unroll
  for (int i = 0; i < 8; ++i)
#pragma unroll
    for (int j = 0; j < 8; ++j)
      acc[i][j] = (f32x4){0.f, 0.f, 0.f, 0.f};

  // stage maps: linear LDS dest, pre-swizzled global source (8 units each
  // for A and B; unit j = 32 rows of the 256-row tile).
  size_t aofs[8], bofs[8];
  int sb[8];
#pragma unroll
  for (int j = 0; j < 8; ++j) {
    const int stored = (j * 256 + tid) * 16;
    const int nat    = stored ^ (((stored >> 7) & 7) << 4);
    const int row    = nat >> 7;            // 0..255
    const int kel    = (nat & 127) >> 1;    // 0..56 step 8
    aofs[j] = (size_t)(m0 + row) * lda + kel;
    bofs[j] = (size_t)(n0 + row) * ldb + kel;
    sb[j]   = j * 4096 + (tid & 192) * 16;  // wave-uniform base (+lane*16 HW)
  }

  auto stage = [&](int d, int k0) {
    char* ab = lds + d * 65536;
    char* bb = ab + 32768;
#pragma unroll
    for (int j = 0; j < 8; ++j) gload_lds16(A + aofs[j] + k0, ab + sb[j]);
#pragma unroll
    for (int j = 0; j < 8; ++j) gload_lds16(B + bofs[j] + k0, bb + sb[j]);
  };

  // swizzled ds_read fragment offsets (wave tile 128x128)
  int ard[8][2], brd[8][2];
#pragma unroll
  for (int mi = 0; mi < 8; ++mi)
#pragma unroll
    for (int kk = 0; kk < 2; ++kk) {
      const int nat = (wm * 128 + mi * 16 + (lane & 15)) * 128 +
                      kk * 64 + (lane >> 4) * 16;
      ard[mi][kk] = nat ^ (((nat >> 7) & 7) << 4);
    }
#pragma unroll
  for (int ni = 0; ni < 8; ++ni)
#pragma unroll
    for (int kk = 0; kk < 2; ++kk) {
      const int nat = (wn * 128 + ni * 16 + (lane & 15)) * 128 +
                      kk * 64 + (lane >> 4) * 16;
      brd[ni][kk] = nat ^ (((nat >> 7) & 7) << 4);
    }

  stage(0, 0);   // prologue: tile 0 -> buf 0 (16 loads/thread in flight)

  const int NT = K >> 6;
  for (int t = 0; t < NT; ++t) {
    const int cur = t & 1;
    if (t + 1 < NT) {
      stage(cur ^ 1, (t + 1) << 6);   // 32 outstanding after issue
      vwait<16>();                    // cur's 16 done; next's 16 in flight
    } else {
      vwait<0>();
    }
    __builtin_amdgcn_s_barrier();
    __builtin_amdgcn_sched_barrier(0);   // no ds_read hoist above barrier

    char* ab = lds + cur * 65536;
    char* bb = ab + 32768;
#pragma unroll
    for (int kk = 0; kk < 2; ++kk) {
      short8 bfv[8];
#pragma unroll
      for (int ni = 0; ni < 8; ++ni)
        bfv[ni] = *reinterpret_cast<const short8*>(bb + brd[ni][kk]);
#pragma unroll
      for (int mi = 0; mi < 8; ++mi) {
        const short8 af = *reinterpret_cast<const short8*>(ab + ard[mi][kk]);
#pragma unroll
        for (int ni = 0; ni < 8; ++ni)
          acc[mi][ni] = __builtin_amdgcn_mfma_f32_16x16x32_bf16(
              af, bfv[ni], acc[mi][ni], 0, 0, 0);
      }
    }
    __builtin_amdgcn_sched_barrier(0);
    __builtin_amdgcn_s_barrier();   // all reads of cur done (lgkm drained by
                                    // MFMA consumption) before overwrite
  }

  // Epilogue: D row=(lane>>4)*4+reg, col=lane&15 (m89-verified)
  const int row0 = m0 + wm * 128 + (lane >> 4) * 4;
  const int col0 = n0 + wn * 128 + (lane & 15);
#pragma unroll
  for (int ni = 0; ni < 8; ++ni) {
    const int c = col0 + ni * 16;
    const float bv = bias[c];
#pragma unroll
    for (int mi = 0; mi < 8; ++mi) {
#pragma unroll
      for (int r = 0; r < 4; ++r) {
        const size_t idx = (size_t)(row0 + mi * 16 + r) * ldc + c;
        float v = acc[mi][ni][r] + bv;
        if (RELU_BF16_OUT) {
          v = v > 0.f ? v : 0.f;
          ((unsigned short*)C)[idx] = f2bf(v);
        } else {
          ((float*)C)[idx] = v;
        }
      }
    }
  }
}

// ---------------------------------------------------------------------------
// 8-phase 256-row GEMM (round-3/9, passing) — used for the L2 GEMM.
// ---------------------------------------------------------------------------
#define PH(ABUF, BBUF, H, KK, STAGE, WAITC)                                    \
  {                                                                            \
    if ((H) == 0) {                                                            \
      _Pragma("unroll")                                                        \
      for (int ni = 0; ni < NB; ++ni)                                          \
        bfr[ni] = *reinterpret_cast<const short8*>((BBUF) + bread[ni][KK]);    \
    }                                                                          \
    short8 afr[4];                                                             \
    _Pragma("unroll")                                                          \
    for (int m2 = 0; m2 < 4; ++m2)                                             \
      afr[m2] = *reinterpret_cast<const short8*>((ABUF) + aread[(H)*4+m2][KK]);\
    STAGE;                                                                     \
    __builtin_amdgcn_s_barrier();                                              \
    asm volatile("s_waitcnt lgkmcnt(0)" ::: "memory");                         \
    __builtin_amdgcn_sched_barrier(0);                                         \
    __builtin_amdgcn_s_setprio(1);                                             \
    _Pragma("unroll")                                                          \
    for (int m2 = 0; m2 < 4; ++m2) {                                           \
      _Pragma("unroll")                                                        \
      for (int ni = 0; ni < NB; ++ni)                                          \
        acc[(H)*4+m2][ni] = __builtin_amdgcn_mfma_f32_16x16x32_bf16(           \
            afr[m2], bfr[ni], acc[(H)*4+m2][ni], 0, 0, 0);                     \
    }                                                                          \
    __builtin_amdgcn_s_setprio(0);                                             \
    WAITC;                                                                     \
    __builtin_amdgcn_s_barrier();                                              \
  }

template <int BN, int RELU_BF16_OUT>
__global__ __launch_bounds__(512, 2)
void gemm8p(const unsigned short* __restrict__ A, int lda,
            const unsigned short* __restrict__ Bp, int ldb,
            const float* __restrict__ bias,
            void* __restrict__ C, int ldc, int K, int nbx) {
  constexpr int PWN     = BN / 4;
  constexpr int NB      = PWN / 16;
  constexpr int LOADS_B = BN / 128;
  constexpr int BHROWS  = BN / 2;
  constexpr int BHSZ    = BHROWS * 128;
  extern __shared__ char lds[];
  char* const A0b = lds;
  char* const A1b = lds + 32768;
  char* const B0b = lds + 65536;
  char* const B1b = lds + 65536 + 2 * BHSZ;

  const int tid  = threadIdx.x;
  const int lane = tid & 63;
  const int wid  = tid >> 6;
  const int wm   = wid >> 2;
  const int wn   = wid & 3;

  const int cpx     = gridDim.x >> 3;
  const int logical = (blockIdx.x & 7) * cpx + (blockIdx.x >> 3);
  const int bx = logical % nbx;
  const int by = logical / nbx;
  const int m0 = by * 256;
  const int n0 = bx * BN;

  f32x4 acc[8][NB];
#pragma unroll
  for (int i = 0; i < 8; ++i)
#pragma unroll
    for (int j = 0; j < NB; ++j)
      acc[i][j] = (f32x4){0.f, 0.f, 0.f, 0.f};

  size_t aofs0, aofs1, bofs0, bofs1 = 0;
  {
    int sr = tid * 16, nat = sr ^ (((sr >> 7) & 7) << 4);
    aofs0 = (size_t)(m0 + (nat >> 7)) * lda + ((nat & 127) >> 1);
    bofs0 = (size_t)(n0 + (nat >> 7)) * ldb + ((nat & 127) >> 1);
    sr = (512 + tid) * 16; nat = sr ^ (((sr >> 7) & 7) << 4);
    aofs1 = (size_t)(m0 + (nat >> 7)) * lda + ((nat & 127) >> 1);
    if (LOADS_B == 2)
      bofs1 = (size_t)(n0 + (nat >> 7)) * ldb + ((nat & 127) >> 1);
  }
  const int dst0 = (tid & 448) * 16;
  const int dst1 = dst0 + 8192;

  auto stA = [&](char* ab, int half, int kel) {
    gload_lds16(A + aofs0 + (size_t)half * 128 * lda + kel, ab + half * 16384 + dst0);
    gload_lds16(A + aofs1 + (size_t)half * 128 * lda + kel, ab + half * 16384 + dst1);
  };
  auto stB = [&](char* bb, int half, int kel) {
    gload_lds16(Bp + bofs0 + (size_t)half * BHROWS * ldb + kel, bb + half * BHSZ + dst0);
    if constexpr (LOADS_B == 2)
      gload_lds16(Bp + bofs1 + (size_t)half * BHROWS * ldb + kel, bb + half * BHSZ + dst1);
  };
  auto waitLB = [&]() {
    if constexpr (LOADS_B == 2) asm volatile("s_waitcnt vmcnt(2)" ::: "memory");
    else                        asm volatile("s_waitcnt vmcnt(1)" ::: "memory");
  };

  int aread[8][2], bread[NB][2];
#pragma unroll
  for (int mi = 0; mi < 8; ++mi)
#pragma unroll
    for (int kk = 0; kk < 2; ++kk) {
      int nat = (wm * 128 + mi * 16 + (lane & 15)) * 128 + kk * 64 + (lane >> 4) * 16;
      aread[mi][kk] = nat ^ (((nat >> 7) & 7) << 4);
    }
#pragma unroll
  for (int ni = 0; ni < NB; ++ni)
#pragma unroll
    for (int kk = 0; kk < 2; ++kk) {
      int nat = (wn * PWN + ni * 16 + (lane & 15)) * 128 + kk * 64 + (lane >> 4) * 16;
      bread[ni][kk] = nat ^ (((nat >> 7) & 7) << 4);
    }

  stB(B0b, 0, 0);
  stB(B0b, 1, 0);
  stA(A0b, 0, 0);
  stA(A0b, 1, 0);
  stB(B1b, 0, 64);
  waitLB();
  __builtin_amdgcn_s_barrier();

  const int niter = K >> 7;
  for (int it = 0; it < niter; ++it) {
    const bool last = (it == niter - 1);
    const int kb = it << 7;
    short8 bfr[NB];
    PH(A0b, B0b, 0, 0, stB(B1b, 1, kb + 64), ((void)0));
    PH(A0b, B0b, 1, 0, stA(A1b, 0, kb + 64), ((void)0));
    PH(A0b, B0b, 0, 1, stA(A1b, 1, kb + 64), ((void)0));
    PH(A0b, B0b, 1, 1, { if (!last) stB(B0b, 0, kb + 128); },
       { if (last) { asm volatile("s_waitcnt vmcnt(0)" ::: "memory"); } else waitLB(); });
    PH(A1b, B1b, 0, 0, { if (!last) stB(B0b, 1, kb + 128); }, ((void)0));
    PH(A1b, B1b, 1, 0, { if (!last) stA(A0b, 0, kb + 128); }, ((void)0));
    PH(A1b, B1b, 0, 1, { if (!last) stA(A0b, 1, kb + 128); }, ((void)0));
    PH(A1b, B1b, 1, 1, { if (!last) stB(B1b, 0, kb + 192); },
       { if (!last) waitLB(); });
  }

  const int row0 = m0 + wm * 128 + (lane >> 4) * 4;
  const int col0 = n0 + wn * PWN + (lane & 15);
#pragma unroll
  for (int ni = 0; ni < NB; ++ni) {
    const int c = col0 + ni * 16;
    const float bv = bias[c];
#pragma unroll
    for (int mi = 0; mi < 8; ++mi) {
#pragma unroll
      for (int r = 0; r < 4; ++r) {
        const size_t idx = (size_t)(row0 + mi * 16 + r) * ldc + c;
        float v = acc[mi][ni][r] + bv;
        if (RELU_BF16_OUT) {
          v = v > 0.f ? v : 0.f;
          ((unsigned short*)C)[idx] = f2bf(v);
        } else {
          ((float*)C)[idx] = v;
        }
      }
    }
  }
}

// ---------------------------------------------------------------------------
// Fallback 128^2 GEMM (round-2, verified) for small-ws configurations.
// ---------------------------------------------------------------------------
template <int A_F32, int RELU_BF16_OUT>
__global__ __launch_bounds__(256, 2)
void gemm_bf16(const void* __restrict__ Ap, int lda,
               const unsigned short* __restrict__ B, int ldb,
               const float* __restrict__ bias,
               void* __restrict__ C, int ldc,
               int K, int beta) {
  __shared__ char lds[32768];
  char* const As = lds;
  char* const Bs = lds + 16384;

  const int tid  = threadIdx.x;
  const int lane = tid & 63;
  const int w    = tid >> 6;
  const int wm   = w >> 1;
  const int wn   = w & 1;
  const int m0   = blockIdx.y * 128;
  const int n0   = blockIdx.x * 128;

  f32x4 acc[4][4];
#pragma unroll
  for (int i = 0; i < 4; ++i)
#pragma unroll
    for (int j = 0; j < 4; ++j)
      acc[i][j] = (f32x4){0.f, 0.f, 0.f, 0.f};

  int srow[4], scol[4], sbase[4];
#pragma unroll
  for (int j = 0; j < 4; ++j) {
    const int stored  = (j * 256 + tid) * 16;
    const int natural = stored ^ (((stored >> 7) & 7) << 4);
    srow[j]  = natural >> 7;
    scol[j]  = (natural & 127) >> 1;
    sbase[j] = (j * 256 + (tid & 192)) * 16;
  }

  size_t agofs[4];
  int ast[4];
  if (A_F32) {
#pragma unroll
    for (int pq = 0; pq < 4; ++pq) {
      const int idx = pq * 256 + tid;
      const int rr  = idx >> 3;
      const int kbe = (idx & 7) * 8;
      agofs[pq] = (size_t)(m0 + rr) * lda + kbe;
      const int nat = rr * 128 + kbe * 2;
      ast[pq] = nat ^ (((nat >> 7) & 7) << 4);
    }
  }

  const int nsteps = K >> 6;
  for (int ks = 0; ks < nsteps; ++ks) {
    const int k0 = ks << 6;
    if (A_F32) {
      const float* Af = (const float*)Ap;
#pragma unroll
      for (int pq = 0; pq < 4; ++pq) {
        const float* sp = Af + agofs[pq] + k0;
        float4 x0 = *reinterpret_cast<const float4*>(sp);
        float4 x1 = *reinterpret_cast<const float4*>(sp + 4);
        ushort8 v;
        v[0] = f2bf(x0.x); v[1] = f2bf(x0.y); v[2] = f2bf(x0.z); v[3] = f2bf(x0.w);
        v[4] = f2bf(x1.x); v[5] = f2bf(x1.y); v[6] = f2bf(x1.z); v[7] = f2bf(x1.w);
        *reinterpret_cast<ushort8*>(As + ast[pq]) = v;
      }
    } else {
      const unsigned short* Ab = (const unsigned short*)Ap;
#pragma unroll
      for (int j = 0; j < 4; ++j)
        gload_lds16(Ab + (size_t)(m0 + srow[j]) * lda + (k0 + scol[j]),
                    As + sbase[j]);
    }
#pragma unroll
    for (int j = 0; j < 4; ++j)
      gload_lds16(B + (size_t)(n0 + srow[j]) * ldb + (k0 + scol[j]),
                  Bs + sbase[j]);
    __syncthreads();

#pragma unroll
    for (int kk = 0; kk < 2; ++kk) {
      const int kb = kk * 64 + (lane >> 4) * 16;
      short8 af[4], bfv[4];
#pragma unroll
      for (int mi = 0; mi < 4; ++mi) {
        int nat = (wm * 64 + mi * 16 + (lane & 15)) * 128 + kb;
        int st  = nat ^ (((nat >> 7) & 7) << 4);
        af[mi] = *reinterpret_cast<const short8*>(As + st);
      }
#pragma unroll
      for (int ni = 0; ni < 4; ++ni) {
        int nat = (wn * 64 + ni * 16 + (lane & 15)) * 128 + kb;
        int st  = nat ^ (((nat >> 7) & 7) << 4);
        bfv[ni] = *reinterpret_cast<const short8*>(Bs + st);
      }
#pragma unroll
      for (int mi = 0; mi < 4; ++mi)
#pragma unroll
        for (int ni = 0; ni < 4; ++ni)
          acc[mi][ni] = __builtin_amdgcn_mfma_f32_16x16x32_bf16(
              af[mi], bfv[ni], acc[mi][ni], 0, 0, 0);
    }
    __syncthreads();
  }

  const int row0 = m0 + wm * 64 + (lane >> 4) * 4;
  const int col0 = n0 + wn * 64 + (lane & 15);
#pragma unroll
  for (int ni = 0; ni < 4; ++ni) {
    const int c = col0 + ni * 16;
    const float bv = beta ? 0.f : bias[c];
#pragma unroll
    for (int mi = 0; mi < 4; ++mi) {
#pragma unroll
      for (int rr = 0; rr < 4; ++rr) {
        const size_t idx = (size_t)(row0 + mi * 16 + rr) * ldc + c;
        float v = acc[mi][ni][rr] + bv;
        if (RELU_BF16_OUT) {
          v = v > 0.f ? v : 0.f;
          ((unsigned short*)C)[idx] = f2bf(v);
        } else {
          if (beta) v += ((float*)C)[idx];
          ((float*)C)[idx] = v;
        }
      }
    }
  }
}

// ---------------------------------------------------------------------------
extern "C" void kernel_launch(void* const* d_in, const int* in_sizes, int n_in,
                              void* d_out, int out_size, void* d_ws, size_t ws_size,
                              hipStream_t stream) {
  const float* X  = (const float*)d_in[0];  // [8192][1024]
  const float* W1 = (const float*)d_in[1];  // [1024][4096]
  const float* b1 = (const float*)d_in[2];  // [4096]
  const float* W2 = (const float*)d_in[3];  // [4096][1024]
  const float* b2 = (const float*)d_in[4];  // [1024]
  float* out = (float*)d_out;               // [8192][1024] f32

  const int M = 8192, H = 1024, I = 4096;
  const size_t MB = 1024 * 1024;

  char* ws = (char*)d_ws;
  unsigned short* W1t = (unsigned short*)ws;            // [I][H] bf16, 8 MB
  unsigned short* W2t = (unsigned short*)(ws + 8 * MB); // [H][I] bf16, 8 MB

  if (ws_size >= 80 * MB) {
    // Fast path. Xbf parked in d_out tail (fully consumed by L1 before the
    // single L2 dispatch writes d_out; stream-serialized).
    unsigned short* Xbf = (unsigned short*)((char*)d_out + 16 * MB);
    unsigned short* Hbf = (unsigned short*)(ws + 16 * MB);   // [M][I] bf16
    prep_fused<<<16384, 256, 0, stream>>>(X, W1, W2, Xbf, W1t, W2t);
    // L1: Hbf = relu(X*W1+b1). Big-wave kernel: 256^2 tiles, 4 waves,
    // per-wave 128x128, grid 16*32=512, LDS 128 KiB.
    gemm_bw<1><<<512, 256, 131072, stream>>>(
        Xbf, H, W1t, H, b1, Hbf, I, H, I / 256);
    // L2: out = Hbf*W2+b2. 8-phase 256x128, grid 256, LDS 96 KiB (verbatim).
    gemm8p<128, 0><<<256, 512, 98304, stream>>>(
        Hbf, I, W2t, I, b2, out, H, I, H / 128);
    return;
  }

  // Fallback: adaptive chunked path (round-2 verified kernels).
  transpose_cvt<<<dim3(I / 32, H / 32), dim3(32, 8), 0, stream>>>(W1, W1t, H, I);
  transpose_cvt<<<dim3(H / 32, I / 32), dim3(32, 8), 0, stream>>>(W2, W2t, I, H);

  int Ic, useXbf;
  unsigned short* Xbf = nullptr;
  unsigned short* Hc;
  if (ws_size >= 64 * MB) {
    Ic = 2048; useXbf = 1;
    Xbf = (unsigned short*)(ws + 16 * MB);
    Hc  = (unsigned short*)(ws + 32 * MB);
  } else if (ws_size >= 48 * MB) {
    Ic = 1024; useXbf = 1;
    Xbf = (unsigned short*)(ws + 16 * MB);
    Hc  = (unsigned short*)(ws + 32 * MB);
  } else if (ws_size >= 32 * MB) {
    Ic = 1024; useXbf = 0;
    Hc  = (unsigned short*)(ws + 16 * MB);
  } else if (ws_size >= 24 * MB) {
    Ic = 512;  useXbf = 0;
    Hc  = (unsigned short*)(ws + 16 * MB);
  } else if (ws_size >= 20 * MB) {
    Ic = 256;  useXbf = 0;
    Hc  = (unsigned short*)(ws + 16 * MB);
  } else {
    Ic = 128;  useXbf = 0;
    Hc  = (unsigned short*)(ws + 16 * MB);
  }

  if (useXbf) {
    int n4 = (M * H) / 4;
    cvt_f32_bf16<<<(n4 + 255) / 256, 256, 0, stream>>>(X, Xbf, n4);
  }

  const int nch = I / Ic;
  for (int c = 0; c < nch; ++c) {
    const int i0 = c * Ic;
    if (useXbf)
      gemm_bf16<0, 1><<<dim3(Ic / 128, M / 128), 256, 0, stream>>>(
          Xbf, H, W1t + (size_t)i0 * H, H, b1 + i0, Hc, Ic, H, 0);
    else
      gemm_bf16<1, 1><<<dim3(Ic / 128, M / 128), 256, 0, stream>>>(
          X, H, W1t + (size_t)i0 * H, H, b1 + i0, Hc, Ic, H, 0);
    gemm_bf16<0, 0><<<dim3(H / 128, M / 128), 256, 0, stream>>>(
        Hc, Ic, W2t + i0, I, b2, out, H, Ic, c > 0);
  }
}

// Round 11
// 165.842 us; speedup vs baseline: 1.2742x; 1.2742x over previous
//
#include <hip/hip_runtime.h>
#include <cstddef>

typedef short short8 __attribute__((ext_vector_type(8)));
typedef unsigned short ushort8 __attribute__((ext_vector_type(8)));
typedef float f32x4 __attribute__((ext_vector_type(4)));

#define AS1(p) ((const __attribute__((address_space(1))) void*)(p))
#define AS3(p) ((__attribute__((address_space(3))) void*)(p))

__device__ __forceinline__ unsigned short f2bf(float f) {
  unsigned int u = __builtin_bit_cast(unsigned int, f);
  u += 0x7FFFu + ((u >> 16) & 1u);   // round-to-nearest-even
  return (unsigned short)(u >> 16);
}

__device__ __forceinline__ void gload_lds16(const void* g, void* l) {
  __builtin_amdgcn_global_load_lds(AS1(g), AS3(l), 16, 0, 0);
}

template <int N>
__device__ __forceinline__ void vwait() {
  asm volatile("s_waitcnt vmcnt(%0)" :: "n"(N) : "memory");
}

// ---------------------------------------------------------------------------
// Fused prep (ONE dispatch): W1 transpose+cvt, W2 transpose+cvt, X f32->bf16.
// blocks [0,4096): W1 -> W1t ; [4096,8192): W2 -> W2t ; [8192,16384): X cvt.
// (round-9 verified)
// ---------------------------------------------------------------------------
__global__ __launch_bounds__(256)
void prep_fused(const float* __restrict__ X,
                const float* __restrict__ W1,
                const float* __restrict__ W2,
                unsigned short* __restrict__ Xbf,
                unsigned short* __restrict__ W1t,
                unsigned short* __restrict__ W2t) {
  const int b   = blockIdx.x;
  const int tid = threadIdx.x;

  if (b >= 8192) {   // ---- X cvt ----
    const size_t i = (size_t)(b - 8192) * 256 + tid;   // 0 .. 2^21-1
    float4 v = *reinterpret_cast<const float4*>(X + i * 4);
    ushort4 o;
    o.x = f2bf(v.x); o.y = f2bf(v.y); o.z = f2bf(v.z); o.w = f2bf(v.w);
    *reinterpret_cast<ushort4*>(Xbf + i * 4) = o;
    return;
  }

  __shared__ float tile[32][33];
  const float* in;
  unsigned short* out;
  int Kd, Nd, n0, k0;
  if (b < 4096) {              // W1: Kd=1024 (H), Nd=4096 (I)
    in = W1; out = W1t; Kd = 1024; Nd = 4096;
    n0 = (b & 127) * 32;
    k0 = (b >> 7) * 32;
  } else {                     // W2: Kd=4096 (I), Nd=1024 (H)
    const int b2 = b - 4096;
    in = W2; out = W2t; Kd = 4096; Nd = 1024;
    n0 = (b2 & 31) * 32;
    k0 = (b2 >> 5) * 32;
  }
  const int tx = tid & 31;
  const int ty = tid >> 5;
#pragma unroll
  for (int i = 0; i < 4; ++i)
    tile[ty + i * 8][tx] = in[(size_t)(k0 + ty + i * 8) * Nd + n0 + tx];
  __syncthreads();
#pragma unroll
  for (int i = 0; i < 4; ++i)
    out[(size_t)(n0 + ty + i * 8) * Kd + k0 + tx] = f2bf(tile[tx][ty + i * 8]);
}

// ---------------------------------------------------------------------------
// Standalone prep kernels (fallback path only).
// ---------------------------------------------------------------------------
__global__ void cvt_f32_bf16(const float* __restrict__ in,
                             unsigned short* __restrict__ out, int n4) {
  int i = blockIdx.x * blockDim.x + threadIdx.x;
  if (i >= n4) return;
  float4 v = *reinterpret_cast<const float4*>(in + (size_t)i * 4);
  ushort4 o;
  o.x = f2bf(v.x); o.y = f2bf(v.y); o.z = f2bf(v.z); o.w = f2bf(v.w);
  *reinterpret_cast<ushort4*>(out + (size_t)i * 4) = o;
}

__global__ void transpose_cvt(const float* __restrict__ in,
                              unsigned short* __restrict__ out,
                              int Kd, int Nd) {
  __shared__ float tile[32][33];
  const int n0 = blockIdx.x * 32;
  const int k0 = blockIdx.y * 32;
  const int tx = threadIdx.x;
  const int ty = threadIdx.y;
#pragma unroll
  for (int i = 0; i < 4; ++i)
    tile[ty + i * 8][tx] = in[(size_t)(k0 + ty + i * 8) * Nd + n0 + tx];
  __syncthreads();
#pragma unroll
  for (int i = 0; i < 4; ++i)
    out[(size_t)(n0 + ty + i * 8) * Kd + k0 + tx] = f2bf(tile[tx][ty + i * 8]);
}

// ---------------------------------------------------------------------------
// COMPILER-FREE dbuf GEMM (round-11 lever): gemm8p geometry (256xBN block,
// 8 waves 2Mx4N, per-wave 128x64, 512 thr) but ONLY 2 barriers + 1 counted
// vmcnt per K-tile and NO lgkm-asm / sched_barrier in the compute region:
// the compiler interleaves the 24 ds_reads with the 64 MFMAs per wave with
// fine-grained lgkmcnt (m97 behavior) instead of my macro-forced drains
// (m141: order-pinning = -40%). Stage(t+1)'s 8/6 loads stay in flight
// across the whole compute of tile t (never drained mid-loop).
// LDS: 2 x (32KB A + BN*128 B). Swizzle a^=((a>>7)&7)<<4 both sides.
// ---------------------------------------------------------------------------
template <int BN, int RELU_BF16_OUT>
__global__ __launch_bounds__(512, 2)
void gemm_cf(const unsigned short* __restrict__ A, int lda,
             const unsigned short* __restrict__ B, int ldb,
             const float* __restrict__ bias,
             void* __restrict__ C, int ldc, int K, int nbx) {
  constexpr int PWN    = BN / 4;          // per-wave N (64 or 32)
  constexpr int NB     = PWN / 16;        // B frags per wave (4 or 2)
  constexpr int AUNITS = 4;               // 8KB stage units for A (32 KB)
  constexpr int BUNITS = BN / 64;         // 8KB stage units for B (4 or 2)
  constexpr int LPT    = AUNITS + BUNITS; // loads per thread per K-tile (8/6)
  constexpr int BUFSZ  = 32768 + BN * 128;
  extern __shared__ char lds[];

  const int tid  = threadIdx.x;
  const int lane = tid & 63;
  const int wid  = tid >> 6;
  const int wm   = wid >> 2;   // 0..1
  const int wn   = wid & 3;    // 0..3

  // bijective XCD-chunked swizzle (grid % 8 == 0)
  const int cpx     = gridDim.x >> 3;
  const int logical = (blockIdx.x & 7) * cpx + (blockIdx.x >> 3);
  const int m0 = (logical / nbx) * 256;
  const int n0 = (logical % nbx) * BN;

  f32x4 acc[8][NB];
#pragma unroll
  for (int i = 0; i < 8; ++i)
#pragma unroll
    for (int j = 0; j < NB; ++j)
      acc[i][j] = (f32x4){0.f, 0.f, 0.f, 0.f};

  // stage maps: linear LDS dest, pre-swizzled global source (8KB units).
  size_t aofs[AUNITS], bofs[BUNITS];
  const int ldst = (tid & 448) * 16;   // wave-uniform base (+lane*16 by HW)
#pragma unroll
  for (int u = 0; u < AUNITS; ++u) {
    const int s   = (u * 512 + tid) * 16;
    const int nat = s ^ (((s >> 7) & 7) << 4);
    aofs[u] = (size_t)(m0 + (nat >> 7)) * lda + ((nat & 127) >> 1);
  }
#pragma unroll
  for (int u = 0; u < BUNITS; ++u) {
    const int s   = (u * 512 + tid) * 16;
    const int nat = s ^ (((s >> 7) & 7) << 4);
    bofs[u] = (size_t)(n0 + (nat >> 7)) * ldb + ((nat & 127) >> 1);
  }

  auto stage = [&](int d, int k0) {
    char* ab = lds + d * BUFSZ;
    char* bb = ab + 32768;
#pragma unroll
    for (int u = 0; u < AUNITS; ++u)
      gload_lds16(A + aofs[u] + k0, ab + u * 8192 + ldst);
#pragma unroll
    for (int u = 0; u < BUNITS; ++u)
      gload_lds16(B + bofs[u] + k0, bb + u * 8192 + ldst);
  };

  // swizzled ds_read fragment offsets
  int ard[8][2], brd[NB][2];
#pragma unroll
  for (int mi = 0; mi < 8; ++mi)
#pragma unroll
    for (int kk = 0; kk < 2; ++kk) {
      const int nat = (wm * 128 + mi * 16 + (lane & 15)) * 128 +
                      kk * 64 + (lane >> 4) * 16;
      ard[mi][kk] = nat ^ (((nat >> 7) & 7) << 4);
    }
#pragma unroll
  for (int ni = 0; ni < NB; ++ni)
#pragma unroll
    for (int kk = 0; kk < 2; ++kk) {
      const int nat = (wn * PWN + ni * 16 + (lane & 15)) * 128 +
                      kk * 64 + (lane >> 4) * 16;
      brd[ni][kk] = 32768 + (nat ^ (((nat >> 7) & 7) << 4));
    }

  stage(0, 0);   // prologue: tile 0 -> buf 0 (LPT loads in flight)

  const int NT = K >> 6;
  for (int t = 0; t < NT; ++t) {
    const int cur = t & 1;
    if (t + 1 < NT) {
      stage(cur ^ 1, (t + 1) << 6);   // 2*LPT outstanding
      vwait<LPT>();                   // cur ready; next's LPT stay in flight
    } else {
      vwait<0>();
    }
    __builtin_amdgcn_s_barrier();     // all waves: cur staged, prev reads done

    char* ab = lds + cur * BUFSZ;
    // Compute the whole K-tile with NO forced waits/order: compiler emits
    // fine-grained lgkmcnt between ds_read and MFMA (m97 behavior).
#pragma unroll
    for (int kk = 0; kk < 2; ++kk) {
      short8 bfv[NB];
#pragma unroll
      for (int ni = 0; ni < NB; ++ni)
        bfv[ni] = *reinterpret_cast<const short8*>(ab + brd[ni][kk]);
#pragma unroll
      for (int mi = 0; mi < 8; ++mi) {
        const short8 af = *reinterpret_cast<const short8*>(ab + ard[mi][kk]);
#pragma unroll
        for (int ni = 0; ni < NB; ++ni)
          acc[mi][ni] = __builtin_amdgcn_mfma_f32_16x16x32_bf16(
              af, bfv[ni], acc[mi][ni], 0, 0, 0);
      }
    }
    __builtin_amdgcn_s_barrier();     // reads of cur done before next stage
  }

  // Epilogue: D row=(lane>>4)*4+reg, col=lane&15 (m89-verified)
  const int row0 = m0 + wm * 128 + (lane >> 4) * 4;
  const int col0 = n0 + wn * PWN + (lane & 15);
#pragma unroll
  for (int ni = 0; ni < NB; ++ni) {
    const int c = col0 + ni * 16;
    const float bv = bias[c];
#pragma unroll
    for (int mi = 0; mi < 8; ++mi) {
#pragma unroll
      for (int r = 0; r < 4; ++r) {
        const size_t idx = (size_t)(row0 + mi * 16 + r) * ldc + c;
        float v = acc[mi][ni][r] + bv;
        if (RELU_BF16_OUT) {
          v = v > 0.f ? v : 0.f;
          ((unsigned short*)C)[idx] = f2bf(v);
        } else {
          ((float*)C)[idx] = v;
        }
      }
    }
  }
}

// ---------------------------------------------------------------------------
// Fallback 128^2 GEMM (round-2, verified) for small-ws configurations.
// ---------------------------------------------------------------------------
template <int A_F32, int RELU_BF16_OUT>
__global__ __launch_bounds__(256, 2)
void gemm_bf16(const void* __restrict__ Ap, int lda,
               const unsigned short* __restrict__ B, int ldb,
               const float* __restrict__ bias,
               void* __restrict__ C, int ldc,
               int K, int beta) {
  __shared__ char lds[32768];
  char* const As = lds;
  char* const Bs = lds + 16384;

  const int tid  = threadIdx.x;
  const int lane = tid & 63;
  const int w    = tid >> 6;
  const int wm   = w >> 1;
  const int wn   = w & 1;
  const int m0   = blockIdx.y * 128;
  const int n0   = blockIdx.x * 128;

  f32x4 acc[4][4];
#pragma unroll
  for (int i = 0; i < 4; ++i)
#pragma unroll
    for (int j = 0; j < 4; ++j)
      acc[i][j] = (f32x4){0.f, 0.f, 0.f, 0.f};

  int srow[4], scol[4], sbase[4];
#pragma unroll
  for (int j = 0; j < 4; ++j) {
    const int stored  = (j * 256 + tid) * 16;
    const int natural = stored ^ (((stored >> 7) & 7) << 4);
    srow[j]  = natural >> 7;
    scol[j]  = (natural & 127) >> 1;
    sbase[j] = (j * 256 + (tid & 192)) * 16;
  }

  size_t agofs[4];
  int ast[4];
  if (A_F32) {
#pragma unroll
    for (int pq = 0; pq < 4; ++pq) {
      const int idx = pq * 256 + tid;
      const int rr  = idx >> 3;
      const int kbe = (idx & 7) * 8;
      agofs[pq] = (size_t)(m0 + rr) * lda + kbe;
      const int nat = rr * 128 + kbe * 2;
      ast[pq] = nat ^ (((nat >> 7) & 7) << 4);
    }
  }

  const int nsteps = K >> 6;
  for (int ks = 0; ks < nsteps; ++ks) {
    const int k0 = ks << 6;
    if (A_F32) {
      const float* Af = (const float*)Ap;
#pragma unroll
      for (int pq = 0; pq < 4; ++pq) {
        const float* sp = Af + agofs[pq] + k0;
        float4 x0 = *reinterpret_cast<const float4*>(sp);
        float4 x1 = *reinterpret_cast<const float4*>(sp + 4);
        ushort8 v;
        v[0] = f2bf(x0.x); v[1] = f2bf(x0.y); v[2] = f2bf(x0.z); v[3] = f2bf(x0.w);
        v[4] = f2bf(x1.x); v[5] = f2bf(x1.y); v[6] = f2bf(x1.z); v[7] = f2bf(x1.w);
        *reinterpret_cast<ushort8*>(As + ast[pq]) = v;
      }
    } else {
      const unsigned short* Ab = (const unsigned short*)Ap;
#pragma unroll
      for (int j = 0; j < 4; ++j)
        gload_lds16(Ab + (size_t)(m0 + srow[j]) * lda + (k0 + scol[j]),
                    As + sbase[j]);
    }
#pragma unroll
    for (int j = 0; j < 4; ++j)
      gload_lds16(B + (size_t)(n0 + srow[j]) * ldb + (k0 + scol[j]),
                  Bs + sbase[j]);
    __syncthreads();

#pragma unroll
    for (int kk = 0; kk < 2; ++kk) {
      const int kb = kk * 64 + (lane >> 4) * 16;
      short8 af[4], bfv[4];
#pragma unroll
      for (int mi = 0; mi < 4; ++mi) {
        int nat = (wm * 64 + mi * 16 + (lane & 15)) * 128 + kb;
        int st  = nat ^ (((nat >> 7) & 7) << 4);
        af[mi] = *reinterpret_cast<const short8*>(As + st);
      }
#pragma unroll
      for (int ni = 0; ni < 4; ++ni) {
        int nat = (wn * 64 + ni * 16 + (lane & 15)) * 128 + kb;
        int st  = nat ^ (((nat >> 7) & 7) << 4);
        bfv[ni] = *reinterpret_cast<const short8*>(Bs + st);
      }
#pragma unroll
      for (int mi = 0; mi < 4; ++mi)
#pragma unroll
        for (int ni = 0; ni < 4; ++ni)
          acc[mi][ni] = __builtin_amdgcn_mfma_f32_16x16x32_bf16(
              af[mi], bfv[ni], acc[mi][ni], 0, 0, 0);
    }
    __syncthreads();
  }

  const int row0 = m0 + wm * 64 + (lane >> 4) * 4;
  const int col0 = n0 + wn * 64 + (lane & 15);
#pragma unroll
  for (int ni = 0; ni < 4; ++ni) {
    const int c = col0 + ni * 16;
    const float bv = beta ? 0.f : bias[c];
#pragma unroll
    for (int mi = 0; mi < 4; ++mi) {
#pragma unroll
      for (int rr = 0; rr < 4; ++rr) {
        const size_t idx = (size_t)(row0 + mi * 16 + rr) * ldc + c;
        float v = acc[mi][ni][rr] + bv;
        if (RELU_BF16_OUT) {
          v = v > 0.f ? v : 0.f;
          ((unsigned short*)C)[idx] = f2bf(v);
        } else {
          if (beta) v += ((float*)C)[idx];
          ((float*)C)[idx] = v;
        }
      }
    }
  }
}

// ---------------------------------------------------------------------------
extern "C" void kernel_launch(void* const* d_in, const int* in_sizes, int n_in,
                              void* d_out, int out_size, void* d_ws, size_t ws_size,
                              hipStream_t stream) {
  const float* X  = (const float*)d_in[0];  // [8192][1024]
  const float* W1 = (const float*)d_in[1];  // [1024][4096]
  const float* b1 = (const float*)d_in[2];  // [4096]
  const float* W2 = (const float*)d_in[3];  // [4096][1024]
  const float* b2 = (const float*)d_in[4];  // [1024]
  float* out = (float*)d_out;               // [8192][1024] f32

  const int M = 8192, H = 1024, I = 4096;
  const size_t MB = 1024 * 1024;

  char* ws = (char*)d_ws;
  unsigned short* W1t = (unsigned short*)ws;            // [I][H] bf16, 8 MB
  unsigned short* W2t = (unsigned short*)(ws + 8 * MB); // [H][I] bf16, 8 MB

  if (ws_size >= 80 * MB) {
    // Fast path. Xbf parked in d_out tail (fully consumed by L1 before the
    // single L2 dispatch writes d_out; stream-serialized).
    unsigned short* Xbf = (unsigned short*)((char*)d_out + 16 * MB);
    unsigned short* Hbf = (unsigned short*)(ws + 16 * MB);   // [M][I] bf16
    prep_fused<<<16384, 256, 0, stream>>>(X, W1, W2, Xbf, W1t, W2t);
    // L1: Hbf = relu(X*W1+b1). 256x256, grid 512, LDS 2x64K = 128 KiB.
    gemm_cf<256, 1><<<512, 512, 131072, stream>>>(
        Xbf, H, W1t, H, b1, Hbf, I, H, I / 256);
    // L2: out = Hbf*W2+b2. 256x128, grid 256, LDS 2x48K = 96 KiB.
    gemm_cf<128, 0><<<256, 512, 98304, stream>>>(
        Hbf, I, W2t, I, b2, out, H, I, H / 128);
    return;
  }

  // Fallback: adaptive chunked path (round-2 verified kernels).
  transpose_cvt<<<dim3(I / 32, H / 32), dim3(32, 8), 0, stream>>>(W1, W1t, H, I);
  transpose_cvt<<<dim3(H / 32, I / 32), dim3(32, 8), 0, stream>>>(W2, W2t, I, H);

  int Ic, useXbf;
  unsigned short* Xbf = nullptr;
  unsigned short* Hc;
  if (ws_size >= 64 * MB) {
    Ic = 2048; useXbf = 1;
    Xbf = (unsigned short*)(ws + 16 * MB);
    Hc  = (unsigned short*)(ws + 32 * MB);
  } else if (ws_size >= 48 * MB) {
    Ic = 1024; useXbf = 1;
    Xbf = (unsigned short*)(ws + 16 * MB);
    Hc  = (unsigned short*)(ws + 32 * MB);
  } else if (ws_size >= 32 * MB) {
    Ic = 1024; useXbf = 0;
    Hc  = (unsigned short*)(ws + 16 * MB);
  } else if (ws_size >= 24 * MB) {
    Ic = 512;  useXbf = 0;
    Hc  = (unsigned short*)(ws + 16 * MB);
  } else if (ws_size >= 20 * MB) {
    Ic = 256;  useXbf = 0;
    Hc  = (unsigned short*)(ws + 16 * MB);
  } else {
    Ic = 128;  useXbf = 0;
    Hc  = (unsigned short*)(ws + 16 * MB);
  }

  if (useXbf) {
    int n4 = (M * H) / 4;
    cvt_f32_bf16<<<(n4 + 255) / 256, 256, 0, stream>>>(X, Xbf, n4);
  }

  const int nch = I / Ic;
  for (int c = 0; c < nch; ++c) {
    const int i0 = c * Ic;
    if (useXbf)
      gemm_bf16<0, 1><<<dim3(Ic / 128, M / 128), 256, 0, stream>>>(
          Xbf, H, W1t + (size_t)i0 * H, H, b1 + i0, Hc, Ic, H, 0);
    else
      gemm_bf16<1, 1><<<dim3(Ic / 128, M / 128), 256, 0, stream>>>(
          X, H, W1t + (size_t)i0 * H, H, b1 + i0, Hc, Ic, H, 0);
    gemm_bf16<0, 0><<<dim3(H / 128, M / 128), 256, 0, stream>>>(
        Hc, Ic, W2t + i0, I, b2, out, H, Ic, c > 0);
  }
}

// Round 12
// 157.527 us; speedup vs baseline: 1.3414x; 1.0528x over previous
//
#include <hip/hip_runtime.h>
#include <cstddef>

typedef short short8 __attribute__((ext_vector_type(8)));
typedef unsigned short ushort8 __attribute__((ext_vector_type(8)));
typedef float f32x4 __attribute__((ext_vector_type(4)));

#define AS1(p) ((const __attribute__((address_space(1))) void*)(p))
#define AS3(p) ((__attribute__((address_space(3))) void*)(p))

__device__ __forceinline__ unsigned short f2bf(float f) {
  unsigned int u = __builtin_bit_cast(unsigned int, f);
  u += 0x7FFFu + ((u >> 16) & 1u);   // round-to-nearest-even
  return (unsigned short)(u >> 16);
}

__device__ __forceinline__ void gload_lds16(const void* g, void* l) {
  __builtin_amdgcn_global_load_lds(AS1(g), AS3(l), 16, 0, 0);
}

// ---------------------------------------------------------------------------
// Fused prep (ONE dispatch): W1 transpose+cvt, W2 transpose+cvt, X f32->bf16.
// blocks [0,4096): W1 -> W1t ; [4096,8192): W2 -> W2t ; [8192,16384): X cvt.
// (round-9 verified)
// ---------------------------------------------------------------------------
__global__ __launch_bounds__(256)
void prep_fused(const float* __restrict__ X,
                const float* __restrict__ W1,
                const float* __restrict__ W2,
                unsigned short* __restrict__ Xbf,
                unsigned short* __restrict__ W1t,
                unsigned short* __restrict__ W2t) {
  const int b   = blockIdx.x;
  const int tid = threadIdx.x;

  if (b >= 8192) {   // ---- X cvt ----
    const size_t i = (size_t)(b - 8192) * 256 + tid;   // 0 .. 2^21-1
    float4 v = *reinterpret_cast<const float4*>(X + i * 4);
    ushort4 o;
    o.x = f2bf(v.x); o.y = f2bf(v.y); o.z = f2bf(v.z); o.w = f2bf(v.w);
    *reinterpret_cast<ushort4*>(Xbf + i * 4) = o;
    return;
  }

  __shared__ float tile[32][33];
  const float* in;
  unsigned short* out;
  int Kd, Nd, n0, k0;
  if (b < 4096) {              // W1: Kd=1024 (H), Nd=4096 (I)
    in = W1; out = W1t; Kd = 1024; Nd = 4096;
    n0 = (b & 127) * 32;
    k0 = (b >> 7) * 32;
  } else {                     // W2: Kd=4096 (I), Nd=1024 (H)
    const int b2 = b - 4096;
    in = W2; out = W2t; Kd = 4096; Nd = 1024;
    n0 = (b2 & 31) * 32;
    k0 = (b2 >> 5) * 32;
  }
  const int tx = tid & 31;
  const int ty = tid >> 5;
#pragma unroll
  for (int i = 0; i < 4; ++i)
    tile[ty + i * 8][tx] = in[(size_t)(k0 + ty + i * 8) * Nd + n0 + tx];
  __syncthreads();
#pragma unroll
  for (int i = 0; i < 4; ++i)
    out[(size_t)(n0 + ty + i * 8) * Kd + k0 + tx] = f2bf(tile[tx][ty + i * 8]);
}

// ---------------------------------------------------------------------------
// Standalone prep kernels (fallback path only).
// ---------------------------------------------------------------------------
__global__ void cvt_f32_bf16(const float* __restrict__ in,
                             unsigned short* __restrict__ out, int n4) {
  int i = blockIdx.x * blockDim.x + threadIdx.x;
  if (i >= n4) return;
  float4 v = *reinterpret_cast<const float4*>(in + (size_t)i * 4);
  ushort4 o;
  o.x = f2bf(v.x); o.y = f2bf(v.y); o.z = f2bf(v.z); o.w = f2bf(v.w);
  *reinterpret_cast<ushort4*>(out + (size_t)i * 4) = o;
}

__global__ void transpose_cvt(const float* __restrict__ in,
                              unsigned short* __restrict__ out,
                              int Kd, int Nd) {
  __shared__ float tile[32][33];
  const int n0 = blockIdx.x * 32;
  const int k0 = blockIdx.y * 32;
  const int tx = threadIdx.x;
  const int ty = threadIdx.y;
#pragma unroll
  for (int i = 0; i < 4; ++i)
    tile[ty + i * 8][tx] = in[(size_t)(k0 + ty + i * 8) * Nd + n0 + tx];
  __syncthreads();
#pragma unroll
  for (int i = 0; i < 4; ++i)
    out[(size_t)(n0 + ty + i * 8) * Kd + k0 + tx] = f2bf(tile[tx][ty + i * 8]);
}

// ---------------------------------------------------------------------------
// 8-phase 256-row GEMM (round-3/9 verified K-loop) with a NEW coalesced
// epilogue: the old 2B/4B scatter stores caused WRITE_SIZE 144MB vs 64
// compulsory + ~50MB write-allocate FETCH — the GEMMs were memory-bound on
// amplified traffic (hbm_bytes/dur == dispatch time), which is why 8 schedule
// variants were all null. Epilogue now bounces the tile through the (dead
// after K-loop) stage LDS and emits 16B fully-coalesced stores.
// Bounce: 256 rows x 512B = 128 KiB, granule-XOR ((row&7)<<4).
// ---------------------------------------------------------------------------
#define PH(ABUF, BBUF, H, KK, STAGE, WAITC)                                    \
  {                                                                            \
    if ((H) == 0) {                                                            \
      _Pragma("unroll")                                                        \
      for (int ni = 0; ni < NB; ++ni)                                          \
        bfr[ni] = *reinterpret_cast<const short8*>((BBUF) + bread[ni][KK]);    \
    }                                                                          \
    short8 afr[4];                                                             \
    _Pragma("unroll")                                                          \
    for (int m2 = 0; m2 < 4; ++m2)                                             \
      afr[m2] = *reinterpret_cast<const short8*>((ABUF) + aread[(H)*4+m2][KK]);\
    STAGE;                                                                     \
    __builtin_amdgcn_s_barrier();                                              \
    asm volatile("s_waitcnt lgkmcnt(0)" ::: "memory");                         \
    __builtin_amdgcn_sched_barrier(0);                                         \
    __builtin_amdgcn_s_setprio(1);                                             \
    _Pragma("unroll")                                                          \
    for (int m2 = 0; m2 < 4; ++m2) {                                           \
      _Pragma("unroll")                                                        \
      for (int ni = 0; ni < NB; ++ni)                                          \
        acc[(H)*4+m2][ni] = __builtin_amdgcn_mfma_f32_16x16x32_bf16(           \
            afr[m2], bfr[ni], acc[(H)*4+m2][ni], 0, 0, 0);                     \
    }                                                                          \
    __builtin_amdgcn_s_setprio(0);                                             \
    WAITC;                                                                     \
    __builtin_amdgcn_s_barrier();                                              \
  }

template <int BN, int RELU_BF16_OUT>
__global__ __launch_bounds__(512, 2)
void gemm8p(const unsigned short* __restrict__ A, int lda,
            const unsigned short* __restrict__ Bp, int ldb,
            const float* __restrict__ bias,
            void* __restrict__ C, int ldc, int K, int nbx) {
  constexpr int PWN     = BN / 4;        // per-wave N (64 or 32)
  constexpr int NB      = PWN / 16;      // B frags per wave (4 or 2)
  constexpr int LOADS_B = BN / 128;      // gload_lds per B-half (2 or 1)
  constexpr int BHROWS  = BN / 2;        // rows per B-half
  constexpr int BHSZ    = BHROWS * 128;  // bytes per B-half
  extern __shared__ char lds[];
  char* const A0b = lds;
  char* const A1b = lds + 32768;
  char* const B0b = lds + 65536;
  char* const B1b = lds + 65536 + 2 * BHSZ;

  const int tid  = threadIdx.x;
  const int lane = tid & 63;
  const int wid  = tid >> 6;
  const int wm   = wid >> 2;
  const int wn   = wid & 3;

  const int cpx     = gridDim.x >> 3;
  const int logical = (blockIdx.x & 7) * cpx + (blockIdx.x >> 3);
  const int bx = logical % nbx;
  const int by = logical / nbx;
  const int m0 = by * 256;
  const int n0 = bx * BN;

  f32x4 acc[8][NB];
#pragma unroll
  for (int i = 0; i < 8; ++i)
#pragma unroll
    for (int j = 0; j < NB; ++j)
      acc[i][j] = (f32x4){0.f, 0.f, 0.f, 0.f};

  size_t aofs0, aofs1, bofs0, bofs1 = 0;
  {
    int sr = tid * 16, nat = sr ^ (((sr >> 7) & 7) << 4);
    aofs0 = (size_t)(m0 + (nat >> 7)) * lda + ((nat & 127) >> 1);
    bofs0 = (size_t)(n0 + (nat >> 7)) * ldb + ((nat & 127) >> 1);
    sr = (512 + tid) * 16; nat = sr ^ (((sr >> 7) & 7) << 4);
    aofs1 = (size_t)(m0 + (nat >> 7)) * lda + ((nat & 127) >> 1);
    if (LOADS_B == 2)
      bofs1 = (size_t)(n0 + (nat >> 7)) * ldb + ((nat & 127) >> 1);
  }
  const int dst0 = (tid & 448) * 16;
  const int dst1 = dst0 + 8192;

  auto stA = [&](char* ab, int half, int kel) {
    gload_lds16(A + aofs0 + (size_t)half * 128 * lda + kel, ab + half * 16384 + dst0);
    gload_lds16(A + aofs1 + (size_t)half * 128 * lda + kel, ab + half * 16384 + dst1);
  };
  auto stB = [&](char* bb, int half, int kel) {
    gload_lds16(Bp + bofs0 + (size_t)half * BHROWS * ldb + kel, bb + half * BHSZ + dst0);
    if constexpr (LOADS_B == 2)
      gload_lds16(Bp + bofs1 + (size_t)half * BHROWS * ldb + kel, bb + half * BHSZ + dst1);
  };
  auto waitLB = [&]() {
    if constexpr (LOADS_B == 2) asm volatile("s_waitcnt vmcnt(2)" ::: "memory");
    else                        asm volatile("s_waitcnt vmcnt(1)" ::: "memory");
  };

  int aread[8][2], bread[NB][2];
#pragma unroll
  for (int mi = 0; mi < 8; ++mi)
#pragma unroll
    for (int kk = 0; kk < 2; ++kk) {
      int nat = (wm * 128 + mi * 16 + (lane & 15)) * 128 + kk * 64 + (lane >> 4) * 16;
      aread[mi][kk] = nat ^ (((nat >> 7) & 7) << 4);
    }
#pragma unroll
  for (int ni = 0; ni < NB; ++ni)
#pragma unroll
    for (int kk = 0; kk < 2; ++kk) {
      int nat = (wn * PWN + ni * 16 + (lane & 15)) * 128 + kk * 64 + (lane >> 4) * 16;
      bread[ni][kk] = nat ^ (((nat >> 7) & 7) << 4);
    }

  stB(B0b, 0, 0);
  stB(B0b, 1, 0);
  stA(A0b, 0, 0);
  stA(A0b, 1, 0);
  stB(B1b, 0, 64);
  waitLB();
  __builtin_amdgcn_s_barrier();

  const int niter = K >> 7;
  for (int it = 0; it < niter; ++it) {
    const bool last = (it == niter - 1);
    const int kb = it << 7;
    short8 bfr[NB];
    PH(A0b, B0b, 0, 0, stB(B1b, 1, kb + 64), ((void)0));
    PH(A0b, B0b, 1, 0, stA(A1b, 0, kb + 64), ((void)0));
    PH(A0b, B0b, 0, 1, stA(A1b, 1, kb + 64), ((void)0));
    PH(A0b, B0b, 1, 1, { if (!last) stB(B0b, 0, kb + 128); },
       { if (last) { asm volatile("s_waitcnt vmcnt(0)" ::: "memory"); } else waitLB(); });
    PH(A1b, B1b, 0, 0, { if (!last) stB(B0b, 1, kb + 128); }, ((void)0));
    PH(A1b, B1b, 1, 0, { if (!last) stA(A0b, 0, kb + 128); }, ((void)0));
    PH(A1b, B1b, 0, 1, { if (!last) stA(A0b, 1, kb + 128); }, ((void)0));
    PH(A1b, B1b, 1, 1, { if (!last) stB(B1b, 0, kb + 192); },
       { if (!last) waitLB(); });
  }

  // ---- Coalesced epilogue via LDS bounce ---------------------------------
  // Stage LDS is dead after the K-loop (last PH ends with a full barrier).
  __syncthreads();
  {
    const int lrow0 = wm * 128 + (lane >> 4) * 4;
    const int lcol0 = wn * PWN + (lane & 15);
#pragma unroll
    for (int ni = 0; ni < NB; ++ni) {
      const int c = lcol0 + ni * 16;
      const float bv = bias[n0 + c];
#pragma unroll
      for (int mi = 0; mi < 8; ++mi) {
#pragma unroll
        for (int r = 0; r < 4; ++r) {
          const int row = lrow0 + mi * 16 + r;
          float v = acc[mi][ni][r] + bv;
          if (RELU_BF16_OUT) {
            v = v > 0.f ? v : 0.f;
            const int byte = (row * 512 + c * 2) ^ ((row & 7) << 4);
            *reinterpret_cast<unsigned short*>(lds + byte) = f2bf(v);
          } else {
            const int byte = (row * 512 + c * 4) ^ ((row & 7) << 4);
            *reinterpret_cast<float*>(lds + byte) = v;
          }
        }
      }
    }
    __syncthreads();
    // 16 granules of 16B per thread; 32 consecutive lanes = 512B contiguous.
#pragma unroll
    for (int i = 0; i < 16; ++i) {
      const int idx  = i * 512 + tid;        // 0..8191
      const int row  = idx >> 5;             // 32 granules per 512B row
      const int g    = idx & 31;
      const int byte = (row * 512 + g * 16) ^ ((row & 7) << 4);
      const uint4 val = *reinterpret_cast<const uint4*>(lds + byte);
      if (RELU_BF16_OUT) {
        unsigned short* dst = (unsigned short*)C +
            (size_t)(m0 + row) * ldc + n0 + g * 8;
        *reinterpret_cast<uint4*>(dst) = val;
      } else {
        float* dst = (float*)C + (size_t)(m0 + row) * ldc + n0 + g * 4;
        *reinterpret_cast<uint4*>(dst) = val;
      }
    }
  }
}

// ---------------------------------------------------------------------------
// Fallback 128^2 GEMM (round-2, verified) for small-ws configurations.
// ---------------------------------------------------------------------------
template <int A_F32, int RELU_BF16_OUT>
__global__ __launch_bounds__(256, 2)
void gemm_bf16(const void* __restrict__ Ap, int lda,
               const unsigned short* __restrict__ B, int ldb,
               const float* __restrict__ bias,
               void* __restrict__ C, int ldc,
               int K, int beta) {
  __shared__ char lds[32768];
  char* const As = lds;
  char* const Bs = lds + 16384;

  const int tid  = threadIdx.x;
  const int lane = tid & 63;
  const int w    = tid >> 6;
  const int wm   = w >> 1;
  const int wn   = w & 1;
  const int m0   = blockIdx.y * 128;
  const int n0   = blockIdx.x * 128;

  f32x4 acc[4][4];
#pragma unroll
  for (int i = 0; i < 4; ++i)
#pragma unroll
    for (int j = 0; j < 4; ++j)
      acc[i][j] = (f32x4){0.f, 0.f, 0.f, 0.f};

  int srow[4], scol[4], sbase[4];
#pragma unroll
  for (int j = 0; j < 4; ++j) {
    const int stored  = (j * 256 + tid) * 16;
    const int natural = stored ^ (((stored >> 7) & 7) << 4);
    srow[j]  = natural >> 7;
    scol[j]  = (natural & 127) >> 1;
    sbase[j] = (j * 256 + (tid & 192)) * 16;
  }

  size_t agofs[4];
  int ast[4];
  if (A_F32) {
#pragma unroll
    for (int pq = 0; pq < 4; ++pq) {
      const int idx = pq * 256 + tid;
      const int rr  = idx >> 3;
      const int kbe = (idx & 7) * 8;
      agofs[pq] = (size_t)(m0 + rr) * lda + kbe;
      const int nat = rr * 128 + kbe * 2;
      ast[pq] = nat ^ (((nat >> 7) & 7) << 4);
    }
  }

  const int nsteps = K >> 6;
  for (int ks = 0; ks < nsteps; ++ks) {
    const int k0 = ks << 6;
    if (A_F32) {
      const float* Af = (const float*)Ap;
#pragma unroll
      for (int pq = 0; pq < 4; ++pq) {
        const float* sp = Af + agofs[pq] + k0;
        float4 x0 = *reinterpret_cast<const float4*>(sp);
        float4 x1 = *reinterpret_cast<const float4*>(sp + 4);
        ushort8 v;
        v[0] = f2bf(x0.x); v[1] = f2bf(x0.y); v[2] = f2bf(x0.z); v[3] = f2bf(x0.w);
        v[4] = f2bf(x1.x); v[5] = f2bf(x1.y); v[6] = f2bf(x1.z); v[7] = f2bf(x1.w);
        *reinterpret_cast<ushort8*>(As + ast[pq]) = v;
      }
    } else {
      const unsigned short* Ab = (const unsigned short*)Ap;
#pragma unroll
      for (int j = 0; j < 4; ++j)
        gload_lds16(Ab + (size_t)(m0 + srow[j]) * lda + (k0 + scol[j]),
                    As + sbase[j]);
    }
#pragma unroll
    for (int j = 0; j < 4; ++j)
      gload_lds16(B + (size_t)(n0 + srow[j]) * ldb + (k0 + scol[j]),
                  Bs + sbase[j]);
    __syncthreads();

#pragma unroll
    for (int kk = 0; kk < 2; ++kk) {
      const int kb = kk * 64 + (lane >> 4) * 16;
      short8 af[4], bfv[4];
#pragma unroll
      for (int mi = 0; mi < 4; ++mi) {
        int nat = (wm * 64 + mi * 16 + (lane & 15)) * 128 + kb;
        int st  = nat ^ (((nat >> 7) & 7) << 4);
        af[mi] = *reinterpret_cast<const short8*>(As + st);
      }
#pragma unroll
      for (int ni = 0; ni < 4; ++ni) {
        int nat = (wn * 64 + ni * 16 + (lane & 15)) * 128 + kb;
        int st  = nat ^ (((nat >> 7) & 7) << 4);
        bfv[ni] = *reinterpret_cast<const short8*>(Bs + st);
      }
#pragma unroll
      for (int mi = 0; mi < 4; ++mi)
#pragma unroll
        for (int ni = 0; ni < 4; ++ni)
          acc[mi][ni] = __builtin_amdgcn_mfma_f32_16x16x32_bf16(
              af[mi], bfv[ni], acc[mi][ni], 0, 0, 0);
    }
    __syncthreads();
  }

  const int row0 = m0 + wm * 64 + (lane >> 4) * 4;
  const int col0 = n0 + wn * 64 + (lane & 15);
#pragma unroll
  for (int ni = 0; ni < 4; ++ni) {
    const int c = col0 + ni * 16;
    const float bv = beta ? 0.f : bias[c];
#pragma unroll
    for (int mi = 0; mi < 4; ++mi) {
#pragma unroll
      for (int rr = 0; rr < 4; ++rr) {
        const size_t idx = (size_t)(row0 + mi * 16 + rr) * ldc + c;
        float v = acc[mi][ni][rr] + bv;
        if (RELU_BF16_OUT) {
          v = v > 0.f ? v : 0.f;
          ((unsigned short*)C)[idx] = f2bf(v);
        } else {
          if (beta) v += ((float*)C)[idx];
          ((float*)C)[idx] = v;
        }
      }
    }
  }
}

// ---------------------------------------------------------------------------
extern "C" void kernel_launch(void* const* d_in, const int* in_sizes, int n_in,
                              void* d_out, int out_size, void* d_ws, size_t ws_size,
                              hipStream_t stream) {
  const float* X  = (const float*)d_in[0];  // [8192][1024]
  const float* W1 = (const float*)d_in[1];  // [1024][4096]
  const float* b1 = (const float*)d_in[2];  // [4096]
  const float* W2 = (const float*)d_in[3];  // [4096][1024]
  const float* b2 = (const float*)d_in[4];  // [1024]
  float* out = (float*)d_out;               // [8192][1024] f32

  const int M = 8192, H = 1024, I = 4096;
  const size_t MB = 1024 * 1024;

  char* ws = (char*)d_ws;
  unsigned short* W1t = (unsigned short*)ws;            // [I][H] bf16, 8 MB
  unsigned short* W2t = (unsigned short*)(ws + 8 * MB); // [H][I] bf16, 8 MB

  if (ws_size >= 80 * MB) {
    // Fast path. Xbf parked in d_out tail (fully consumed by L1 before the
    // single L2 dispatch writes d_out; stream-serialized).
    unsigned short* Xbf = (unsigned short*)((char*)d_out + 16 * MB);
    unsigned short* Hbf = (unsigned short*)(ws + 16 * MB);   // [M][I] bf16
    prep_fused<<<16384, 256, 0, stream>>>(X, W1, W2, Xbf, W1t, W2t);
    // L1: Hbf = relu(X*W1+b1). 256x256 tiles, grid 512, LDS 128 KiB.
    gemm8p<256, 1><<<512, 512, 131072, stream>>>(Xbf, H, W1t, H, b1, Hbf, I, H, I / 256);
    // L2: out = Hbf*W2+b2. 256x128 tiles, grid 256, LDS 128 KiB (f32 bounce).
    gemm8p<128, 0><<<256, 512, 131072, stream>>>(Hbf, I, W2t, I, b2, out, H, I, H / 128);
    return;
  }

  // Fallback: adaptive chunked path (round-2 verified kernels).
  transpose_cvt<<<dim3(I / 32, H / 32), dim3(32, 8), 0, stream>>>(W1, W1t, H, I);
  transpose_cvt<<<dim3(H / 32, I / 32), dim3(32, 8), 0, stream>>>(W2, W2t, I, H);

  int Ic, useXbf;
  unsigned short* Xbf = nullptr;
  unsigned short* Hc;
  if (ws_size >= 64 * MB) {
    Ic = 2048; useXbf = 1;
    Xbf = (unsigned short*)(ws + 16 * MB);
    Hc  = (unsigned short*)(ws + 32 * MB);
  } else if (ws_size >= 48 * MB) {
    Ic = 1024; useXbf = 1;
    Xbf = (unsigned short*)(ws + 16 * MB);
    Hc  = (unsigned short*)(ws + 32 * MB);
  } else if (ws_size >= 32 * MB) {
    Ic = 1024; useXbf = 0;
    Hc  = (unsigned short*)(ws + 16 * MB);
  } else if (ws_size >= 24 * MB) {
    Ic = 512;  useXbf = 0;
    Hc  = (unsigned short*)(ws + 16 * MB);
  } else if (ws_size >= 20 * MB) {
    Ic = 256;  useXbf = 0;
    Hc  = (unsigned short*)(ws + 16 * MB);
  } else {
    Ic = 128;  useXbf = 0;
    Hc  = (unsigned short*)(ws + 16 * MB);
  }

  if (useXbf) {
    int n4 = (M * H) / 4;
    cvt_f32_bf16<<<(n4 + 255) / 256, 256, 0, stream>>>(X, Xbf, n4);
  }

  const int nch = I / Ic;
  for (int c = 0; c < nch; ++c) {
    const int i0 = c * Ic;
    if (useXbf)
      gemm_bf16<0, 1><<<dim3(Ic / 128, M / 128), 256, 0, stream>>>(
          Xbf, H, W1t + (size_t)i0 * H, H, b1 + i0, Hc, Ic, H, 0);
    else
      gemm_bf16<1, 1><<<dim3(Ic / 128, M / 128), 256, 0, stream>>>(
          X, H, W1t + (size_t)i0 * H, H, b1 + i0, Hc, Ic, H, 0);
    gemm_bf16<0, 0><<<dim3(H / 128, M / 128), 256, 0, stream>>>(
        Hc, Ic, W2t + i0, I, b2, out, H, Ic, c > 0);
  }
}

// Round 13
// 157.436 us; speedup vs baseline: 1.3422x; 1.0006x over previous
//
#include <hip/hip_runtime.h>
#include <cstddef>

typedef short short8 __attribute__((ext_vector_type(8)));
typedef unsigned short ushort8 __attribute__((ext_vector_type(8)));
typedef float f32x4 __attribute__((ext_vector_type(4)));

#define AS1(p) ((const __attribute__((address_space(1))) void*)(p))
#define AS3(p) ((__attribute__((address_space(3))) void*)(p))

__device__ __forceinline__ unsigned short f2bf(float f) {
  unsigned int u = __builtin_bit_cast(unsigned int, f);
  u += 0x7FFFu + ((u >> 16) & 1u);   // round-to-nearest-even
  return (unsigned short)(u >> 16);
}

__device__ __forceinline__ void gload_lds16(const void* g, void* l) {
  __builtin_amdgcn_global_load_lds(AS1(g), AS3(l), 16, 0, 0);
}

template <int N>
__device__ __forceinline__ void vwait() {
  asm volatile("s_waitcnt vmcnt(%0)" :: "n"(N) : "memory");
}

// ---------------------------------------------------------------------------
// Fused prep (ONE dispatch): W1 transpose+cvt, W2 transpose+cvt, X f32->bf16.
// (round-9 verified)
// ---------------------------------------------------------------------------
__global__ __launch_bounds__(256)
void prep_fused(const float* __restrict__ X,
                const float* __restrict__ W1,
                const float* __restrict__ W2,
                unsigned short* __restrict__ Xbf,
                unsigned short* __restrict__ W1t,
                unsigned short* __restrict__ W2t) {
  const int b   = blockIdx.x;
  const int tid = threadIdx.x;

  if (b >= 8192) {   // ---- X cvt ----
    const size_t i = (size_t)(b - 8192) * 256 + tid;   // 0 .. 2^21-1
    float4 v = *reinterpret_cast<const float4*>(X + i * 4);
    ushort4 o;
    o.x = f2bf(v.x); o.y = f2bf(v.y); o.z = f2bf(v.z); o.w = f2bf(v.w);
    *reinterpret_cast<ushort4*>(Xbf + i * 4) = o;
    return;
  }

  __shared__ float tile[32][33];
  const float* in;
  unsigned short* out;
  int Kd, Nd, n0, k0;
  if (b < 4096) {              // W1: Kd=1024 (H), Nd=4096 (I)
    in = W1; out = W1t; Kd = 1024; Nd = 4096;
    n0 = (b & 127) * 32;
    k0 = (b >> 7) * 32;
  } else {                     // W2: Kd=4096 (I), Nd=1024 (H)
    const int b2 = b - 4096;
    in = W2; out = W2t; Kd = 4096; Nd = 1024;
    n0 = (b2 & 31) * 32;
    k0 = (b2 >> 5) * 32;
  }
  const int tx = tid & 31;
  const int ty = tid >> 5;
#pragma unroll
  for (int i = 0; i < 4; ++i)
    tile[ty + i * 8][tx] = in[(size_t)(k0 + ty + i * 8) * Nd + n0 + tx];
  __syncthreads();
#pragma unroll
  for (int i = 0; i < 4; ++i)
    out[(size_t)(n0 + ty + i * 8) * Kd + k0 + tx] = f2bf(tile[tx][ty + i * 8]);
}

// ---------------------------------------------------------------------------
// Standalone prep kernels (fallback path only).
// ---------------------------------------------------------------------------
__global__ void cvt_f32_bf16(const float* __restrict__ in,
                             unsigned short* __restrict__ out, int n4) {
  int i = blockIdx.x * blockDim.x + threadIdx.x;
  if (i >= n4) return;
  float4 v = *reinterpret_cast<const float4*>(in + (size_t)i * 4);
  ushort4 o;
  o.x = f2bf(v.x); o.y = f2bf(v.y); o.z = f2bf(v.z); o.w = f2bf(v.w);
  *reinterpret_cast<ushort4*>(out + (size_t)i * 4) = o;
}

__global__ void transpose_cvt(const float* __restrict__ in,
                              unsigned short* __restrict__ out,
                              int Kd, int Nd) {
  __shared__ float tile[32][33];
  const int n0 = blockIdx.x * 32;
  const int k0 = blockIdx.y * 32;
  const int tx = threadIdx.x;
  const int ty = threadIdx.y;
#pragma unroll
  for (int i = 0; i < 4; ++i)
    tile[ty + i * 8][tx] = in[(size_t)(k0 + ty + i * 8) * Nd + n0 + tx];
  __syncthreads();
#pragma unroll
  for (int i = 0; i < 4; ++i)
    out[(size_t)(n0 + ty + i * 8) * Kd + k0 + tx] = f2bf(tile[tx][ty + i * 8]);
}

// ---------------------------------------------------------------------------
// QUADRANT-PHASE GEMM (round-13): 256xBN tile, 8 waves, BK=64.
// Phase = C-quadrant (QM,QN) over full K=64 -> phase p needs ONLY A-half QM
// and B-half QN. Halves are consumed progressively (A-h1/B-h1 first needed
// at P3/P2), so each half staged 3-4 phases ahead of use; uniform counted
// waits {2LA, LA+LB, 2LB, LB+LA} keep a genuine 3-half-tile-deep pipeline
// (m218 structure) and ONE barrier per phase (4/K-tile vs gemm8p's 8).
// 2-deep dbuf per half: stage of tile t+1 never touches buffers being read.
// LDS: A 4x16KB + B 4xBHB; swizzle a^=((a>>7)&7)<<4 both sides (verified
// 0-conflict). Coalesced bounce epilogue (r12, -11us verified).
// ---------------------------------------------------------------------------
#define QPH(D, QM, QN, RDA, RDB, STAGE, WAITC)                                 \
  {                                                                            \
    if (RDA) {                                                                 \
      char* ab = lds + (D) * 32768 + (QM) * 16384;                             \
      _Pragma("unroll")                                                        \
      for (int mi = 0; mi < 4; ++mi)                                           \
        _Pragma("unroll")                                                      \
        for (int kk = 0; kk < 2; ++kk)                                         \
          aF[mi][kk] = *reinterpret_cast<const short8*>(ab + ardA[mi][kk]);    \
    }                                                                          \
    if (RDB) {                                                                 \
      char* bb = lds + 65536 + (D) * 2 * BHB + (QN) * BHB;                     \
      _Pragma("unroll")                                                        \
      for (int ni = 0; ni < NF; ++ni)                                          \
        _Pragma("unroll")                                                      \
        for (int kk = 0; kk < 2; ++kk)                                         \
          bF[QN][ni][kk] = *reinterpret_cast<const short8*>(bb + brdB[ni][kk]);\
    }                                                                          \
    STAGE;                                                                     \
    __builtin_amdgcn_s_setprio(1);                                             \
    _Pragma("unroll")                                                          \
    for (int mi = 0; mi < 4; ++mi)                                             \
      _Pragma("unroll")                                                        \
      for (int ni = 0; ni < NF; ++ni)                                          \
        _Pragma("unroll")                                                      \
        for (int kk = 0; kk < 2; ++kk)                                         \
          acc[QM][QN][mi][ni] = __builtin_amdgcn_mfma_f32_16x16x32_bf16(       \
              aF[mi][kk], bF[QN][ni][kk], acc[QM][QN][mi][ni], 0, 0, 0);       \
    __builtin_amdgcn_s_setprio(0);                                             \
    WAITC;                                                                     \
    __builtin_amdgcn_s_barrier();                                              \
  }

template <int BN, int RELU_BF16_OUT>
__global__ __launch_bounds__(512, 2)
void gemm_q(const unsigned short* __restrict__ A, int lda,
            const unsigned short* __restrict__ B, int ldb,
            const float* __restrict__ bias,
            void* __restrict__ C, int ldc, int K, int nbx) {
  constexpr int NF  = BN / 128;        // B frags per wave per quadrant (2/1)
  constexpr int LA  = 2;               // loads/thread per A-half stage
  constexpr int LB  = BN / 128;        // loads/thread per B-half stage (2/1)
  constexpr int BHB = BN * 64;         // bytes per B half-buffer (16K/8K)
  extern __shared__ char lds[];

  const int tid  = threadIdx.x;
  const int lane = tid & 63;
  const int wid  = tid >> 6;
  const int wm2  = wid >> 2;   // 0..1 (64-row slice within 128-row quadrant)
  const int wn4  = wid & 3;    // 0..3 (col slice within quadrant)

  // bijective XCD-chunked swizzle (grid % 8 == 0)
  const int cpx     = gridDim.x >> 3;
  const int logical = (blockIdx.x & 7) * cpx + (blockIdx.x >> 3);
  const int m0 = (logical / nbx) * 256;
  const int n0 = (logical % nbx) * BN;

  f32x4 acc[2][2][4][NF];
#pragma unroll
  for (int a = 0; a < 2; ++a)
#pragma unroll
    for (int b = 0; b < 2; ++b)
#pragma unroll
      for (int c = 0; c < 4; ++c)
#pragma unroll
        for (int d = 0; d < NF; ++d)
          acc[a][b][c][d] = (f32x4){0.f, 0.f, 0.f, 0.f};

  // stage maps: linear LDS dest, pre-swizzled global source.
  size_t aG[2], bG[2];
#pragma unroll
  for (int u = 0; u < 2; ++u) {
    const int s   = (u * 512 + tid) * 16;
    const int nat = s ^ (((s >> 7) & 7) << 4);
    aG[u] = (size_t)(m0 + (nat >> 7)) * lda + ((nat & 127) >> 1);
    if (u < LB)
      bG[u] = (size_t)(n0 + (nat >> 7)) * ldb + ((nat & 127) >> 1);
    else
      bG[u] = 0;
  }
  const int wb0 = (tid & 448) * 16;    // wave-uniform base (+lane*16 by HW)
  const int wb1 = 8192 + wb0;

  auto stageA = [&](int d, int h, int kel) {
    char* dst = lds + d * 32768 + h * 16384;
    gload_lds16(A + aG[0] + (size_t)h * 128 * lda + kel, dst + wb0);
    gload_lds16(A + aG[1] + (size_t)h * 128 * lda + kel, dst + wb1);
  };
  auto stageB = [&](int d, int h, int kel) {
    char* dst = lds + 65536 + d * 2 * BHB + h * BHB;
    gload_lds16(B + bG[0] + (size_t)h * (BN / 2) * ldb + kel, dst + wb0);
    if constexpr (LB == 2)
      gload_lds16(B + bG[1] + (size_t)h * (BN / 2) * ldb + kel, dst + wb1);
  };

  // swizzled ds_read offsets (within one half-buffer)
  int ardA[4][2], brdB[NF][2];
#pragma unroll
  for (int mi = 0; mi < 4; ++mi)
#pragma unroll
    for (int kk = 0; kk < 2; ++kk) {
      const int nat = (wm2 * 64 + mi * 16 + (lane & 15)) * 128 +
                      kk * 64 + (lane >> 4) * 16;
      ardA[mi][kk] = nat ^ (((nat >> 7) & 7) << 4);
    }
#pragma unroll
  for (int ni = 0; ni < NF; ++ni)
#pragma unroll
    for (int kk = 0; kk < 2; ++kk) {
      const int nat = (wn4 * (BN / 8) + ni * 16 + (lane & 15)) * 128 +
                      kk * 64 + (lane >> 4) * 16;
      brdB[ni][kk] = nat ^ (((nat >> 7) & 7) << 4);
    }

  // prologue: tile 0 halves in order [A0, B0, B1, A1]; leave B1,A1 in flight
  stageA(0, 0, 0);
  stageB(0, 0, 0);
  stageB(0, 1, 0);
  stageA(0, 1, 0);
  vwait<LA + LB>();
  __builtin_amdgcn_s_barrier();

  short8 aF[4][2];
  short8 bF[2][NF][2];
  const int NT = K >> 6;
  for (int it = 0; it < NT - 1; ++it) {
    const int d = it & 1, e = d ^ 1;
    const int nk = (it + 1) << 6;
    QPH(d, 0, 0, 1, 1, stageA(e, 0, nk), vwait<2 * LA>());
    QPH(d, 0, 1, 0, 1, stageB(e, 0, nk), (vwait<LA + LB>()));
    QPH(d, 1, 0, 1, 0, stageB(e, 1, nk), vwait<2 * LB>());
    QPH(d, 1, 1, 0, 0, stageA(e, 1, nk), (vwait<LB + LA>()));
  }
  {
    const int d = (NT - 1) & 1;
    QPH(d, 0, 0, 1, 1, ((void)0), vwait<LA>());
    QPH(d, 0, 1, 0, 1, ((void)0), vwait<0>());
    QPH(d, 1, 0, 1, 0, ((void)0), ((void)0));
    QPH(d, 1, 1, 0, 0, ((void)0), ((void)0));
  }

  // ---- Coalesced epilogue via LDS bounce (r12, verified) -----------------
  __syncthreads();
  {
#pragma unroll
    for (int qm = 0; qm < 2; ++qm) {
#pragma unroll
      for (int qn = 0; qn < 2; ++qn) {
#pragma unroll
        for (int ni = 0; ni < NF; ++ni) {
          const int c = qn * (BN / 2) + wn4 * (BN / 8) + ni * 16 + (lane & 15);
          const float bv = bias[n0 + c];
#pragma unroll
          for (int mi = 0; mi < 4; ++mi) {
#pragma unroll
            for (int rr = 0; rr < 4; ++rr) {
              const int row = qm * 128 + wm2 * 64 + mi * 16 +
                              (lane >> 4) * 4 + rr;
              float v = acc[qm][qn][mi][ni][rr] + bv;
              if (RELU_BF16_OUT) {
                v = v > 0.f ? v : 0.f;
                const int byte = (row * 512 + c * 2) ^ ((row & 7) << 4);
                *reinterpret_cast<unsigned short*>(lds + byte) = f2bf(v);
              } else {
                const int byte = (row * 512 + c * 4) ^ ((row & 7) << 4);
                *reinterpret_cast<float*>(lds + byte) = v;
              }
            }
          }
        }
      }
    }
    __syncthreads();
#pragma unroll
    for (int i = 0; i < 16; ++i) {
      const int idx  = i * 512 + tid;        // 0..8191
      const int row  = idx >> 5;
      const int g    = idx & 31;
      const int byte = (row * 512 + g * 16) ^ ((row & 7) << 4);
      const uint4 val = *reinterpret_cast<const uint4*>(lds + byte);
      if (RELU_BF16_OUT) {
        unsigned short* dst = (unsigned short*)C +
            (size_t)(m0 + row) * ldc + n0 + g * 8;
        *reinterpret_cast<uint4*>(dst) = val;
      } else {
        float* dst = (float*)C + (size_t)(m0 + row) * ldc + n0 + g * 4;
        *reinterpret_cast<uint4*>(dst) = val;
      }
    }
  }
}

// ---------------------------------------------------------------------------
// Fallback 128^2 GEMM (round-2, verified) for small-ws configurations.
// ---------------------------------------------------------------------------
template <int A_F32, int RELU_BF16_OUT>
__global__ __launch_bounds__(256, 2)
void gemm_bf16(const void* __restrict__ Ap, int lda,
               const unsigned short* __restrict__ B, int ldb,
               const float* __restrict__ bias,
               void* __restrict__ C, int ldc,
               int K, int beta) {
  __shared__ char lds[32768];
  char* const As = lds;
  char* const Bs = lds + 16384;

  const int tid  = threadIdx.x;
  const int lane = tid & 63;
  const int w    = tid >> 6;
  const int wm   = w >> 1;
  const int wn   = w & 1;
  const int m0   = blockIdx.y * 128;
  const int n0   = blockIdx.x * 128;

  f32x4 acc[4][4];
#pragma unroll
  for (int i = 0; i < 4; ++i)
#pragma unroll
    for (int j = 0; j < 4; ++j)
      acc[i][j] = (f32x4){0.f, 0.f, 0.f, 0.f};

  int srow[4], scol[4], sbase[4];
#pragma unroll
  for (int j = 0; j < 4; ++j) {
    const int stored  = (j * 256 + tid) * 16;
    const int natural = stored ^ (((stored >> 7) & 7) << 4);
    srow[j]  = natural >> 7;
    scol[j]  = (natural & 127) >> 1;
    sbase[j] = (j * 256 + (tid & 192)) * 16;
  }

  size_t agofs[4];
  int ast[4];
  if (A_F32) {
#pragma unroll
    for (int pq = 0; pq < 4; ++pq) {
      const int idx = pq * 256 + tid;
      const int rr  = idx >> 3;
      const int kbe = (idx & 7) * 8;
      agofs[pq] = (size_t)(m0 + rr) * lda + kbe;
      const int nat = rr * 128 + kbe * 2;
      ast[pq] = nat ^ (((nat >> 7) & 7) << 4);
    }
  }

  const int nsteps = K >> 6;
  for (int ks = 0; ks < nsteps; ++ks) {
    const int k0 = ks << 6;
    if (A_F32) {
      const float* Af = (const float*)Ap;
#pragma unroll
      for (int pq = 0; pq < 4; ++pq) {
        const float* sp = Af + agofs[pq] + k0;
        float4 x0 = *reinterpret_cast<const float4*>(sp);
        float4 x1 = *reinterpret_cast<const float4*>(sp + 4);
        ushort8 v;
        v[0] = f2bf(x0.x); v[1] = f2bf(x0.y); v[2] = f2bf(x0.z); v[3] = f2bf(x0.w);
        v[4] = f2bf(x1.x); v[5] = f2bf(x1.y); v[6] = f2bf(x1.z); v[7] = f2bf(x1.w);
        *reinterpret_cast<ushort8*>(As + ast[pq]) = v;
      }
    } else {
      const unsigned short* Ab = (const unsigned short*)Ap;
#pragma unroll
      for (int j = 0; j < 4; ++j)
        gload_lds16(Ab + (size_t)(m0 + srow[j]) * lda + (k0 + scol[j]),
                    As + sbase[j]);
    }
#pragma unroll
    for (int j = 0; j < 4; ++j)
      gload_lds16(B + (size_t)(n0 + srow[j]) * ldb + (k0 + scol[j]),
                  Bs + sbase[j]);
    __syncthreads();

#pragma unroll
    for (int kk = 0; kk < 2; ++kk) {
      const int kb = kk * 64 + (lane >> 4) * 16;
      short8 af[4], bfv[4];
#pragma unroll
      for (int mi = 0; mi < 4; ++mi) {
        int nat = (wm * 64 + mi * 16 + (lane & 15)) * 128 + kb;
        int st  = nat ^ (((nat >> 7) & 7) << 4);
        af[mi] = *reinterpret_cast<const short8*>(As + st);
      }
#pragma unroll
      for (int ni = 0; ni < 4; ++ni) {
        int nat = (wn * 64 + ni * 16 + (lane & 15)) * 128 + kb;
        int st  = nat ^ (((nat >> 7) & 7) << 4);
        bfv[ni] = *reinterpret_cast<const short8*>(Bs + st);
      }
#pragma unroll
      for (int mi = 0; mi < 4; ++mi)
#pragma unroll
        for (int ni = 0; ni < 4; ++ni)
          acc[mi][ni] = __builtin_amdgcn_mfma_f32_16x16x32_bf16(
              af[mi], bfv[ni], acc[mi][ni], 0, 0, 0);
    }
    __syncthreads();
  }

  const int row0 = m0 + wm * 64 + (lane >> 4) * 4;
  const int col0 = n0 + wn * 64 + (lane & 15);
#pragma unroll
  for (int ni = 0; ni < 4; ++ni) {
    const int c = col0 + ni * 16;
    const float bv = beta ? 0.f : bias[c];
#pragma unroll
    for (int mi = 0; mi < 4; ++mi) {
#pragma unroll
      for (int rr = 0; rr < 4; ++rr) {
        const size_t idx = (size_t)(row0 + mi * 16 + rr) * ldc + c;
        float v = acc[mi][ni][rr] + bv;
        if (RELU_BF16_OUT) {
          v = v > 0.f ? v : 0.f;
          ((unsigned short*)C)[idx] = f2bf(v);
        } else {
          if (beta) v += ((float*)C)[idx];
          ((float*)C)[idx] = v;
        }
      }
    }
  }
}

// ---------------------------------------------------------------------------
extern "C" void kernel_launch(void* const* d_in, const int* in_sizes, int n_in,
                              void* d_out, int out_size, void* d_ws, size_t ws_size,
                              hipStream_t stream) {
  const float* X  = (const float*)d_in[0];  // [8192][1024]
  const float* W1 = (const float*)d_in[1];  // [1024][4096]
  const float* b1 = (const float*)d_in[2];  // [4096]
  const float* W2 = (const float*)d_in[3];  // [4096][1024]
  const float* b2 = (const float*)d_in[4];  // [1024]
  float* out = (float*)d_out;               // [8192][1024] f32

  const int M = 8192, H = 1024, I = 4096;
  const size_t MB = 1024 * 1024;

  char* ws = (char*)d_ws;
  unsigned short* W1t = (unsigned short*)ws;            // [I][H] bf16, 8 MB
  unsigned short* W2t = (unsigned short*)(ws + 8 * MB); // [H][I] bf16, 8 MB

  if (ws_size >= 80 * MB) {
    // Fast path. Xbf parked in d_out tail (fully consumed by L1 before the
    // single L2 dispatch writes d_out; stream-serialized).
    unsigned short* Xbf = (unsigned short*)((char*)d_out + 16 * MB);
    unsigned short* Hbf = (unsigned short*)(ws + 16 * MB);   // [M][I] bf16
    prep_fused<<<16384, 256, 0, stream>>>(X, W1, W2, Xbf, W1t, W2t);
    // L1: Hbf = relu(X*W1+b1). quadrant-phase 256x256, grid 512, 128 KiB.
    gemm_q<256, 1><<<512, 512, 131072, stream>>>(
        Xbf, H, W1t, H, b1, Hbf, I, H, I / 256);
    // L2: out = Hbf*W2+b2. quadrant-phase 256x128, grid 256, 128 KiB.
    gemm_q<128, 0><<<256, 512, 131072, stream>>>(
        Hbf, I, W2t, I, b2, out, H, I, H / 128);
    return;
  }

  // Fallback: adaptive chunked path (round-2 verified kernels).
  transpose_cvt<<<dim3(I / 32, H / 32), dim3(32, 8), 0, stream>>>(W1, W1t, H, I);
  transpose_cvt<<<dim3(H / 32, I / 32), dim3(32, 8), 0, stream>>>(W2, W2t, I, H);

  int Ic, useXbf;
  unsigned short* Xbf = nullptr;
  unsigned short* Hc;
  if (ws_size >= 64 * MB) {
    Ic = 2048; useXbf = 1;
    Xbf = (unsigned short*)(ws + 16 * MB);
    Hc  = (unsigned short*)(ws + 32 * MB);
  } else if (ws_size >= 48 * MB) {
    Ic = 1024; useXbf = 1;
    Xbf = (unsigned short*)(ws + 16 * MB);
    Hc  = (unsigned short*)(ws + 32 * MB);
  } else if (ws_size >= 32 * MB) {
    Ic = 1024; useXbf = 0;
    Hc  = (unsigned short*)(ws + 16 * MB);
  } else if (ws_size >= 24 * MB) {
    Ic = 512;  useXbf = 0;
    Hc  = (unsigned short*)(ws + 16 * MB);
  } else if (ws_size >= 20 * MB) {
    Ic = 256;  useXbf = 0;
    Hc  = (unsigned short*)(ws + 16 * MB);
  } else {
    Ic = 128;  useXbf = 0;
    Hc  = (unsigned short*)(ws + 16 * MB);
  }

  if (useXbf) {
    int n4 = (M * H) / 4;
    cvt_f32_bf16<<<(n4 + 255) / 256, 256, 0, stream>>>(X, Xbf, n4);
  }

  const int nch = I / Ic;
  for (int c = 0; c < nch; ++c) {
    const int i0 = c * Ic;
    if (useXbf)
      gemm_bf16<0, 1><<<dim3(Ic / 128, M / 128), 256, 0, stream>>>(
          Xbf, H, W1t + (size_t)i0 * H, H, b1 + i0, Hc, Ic, H, 0);
    else
      gemm_bf16<1, 1><<<dim3(Ic / 128, M / 128), 256, 0, stream>>>(
          X, H, W1t + (size_t)i0 * H, H, b1 + i0, Hc, Ic, H, 0);
    gemm_bf16<0, 0><<<dim3(H / 128, M / 128), 256, 0, stream>>>(
        Hc, Ic, W2t + i0, I, b2, out, H, Ic, c > 0);
  }
}

// Round 15
// 157.223 us; speedup vs baseline: 1.3440x; 1.0014x over previous
//
#include <hip/hip_runtime.h>
#include <cstddef>

typedef short short8 __attribute__((ext_vector_type(8)));
typedef unsigned short ushort8 __attribute__((ext_vector_type(8)));
typedef float f32x4 __attribute__((ext_vector_type(4)));

#define AS1(p) ((const __attribute__((address_space(1))) void*)(p))
#define AS3(p) ((__attribute__((address_space(3))) void*)(p))

__device__ __forceinline__ unsigned short f2bf(float f) {
  unsigned int u = __builtin_bit_cast(unsigned int, f);
  u += 0x7FFFu + ((u >> 16) & 1u);   // round-to-nearest-even
  return (unsigned short)(u >> 16);
}

__device__ __forceinline__ void gload_lds16(const void* g, void* l) {
  __builtin_amdgcn_global_load_lds(AS1(g), AS3(l), 16, 0, 0);
}

template <int N>
__device__ __forceinline__ void vwait() {
  asm volatile("s_waitcnt vmcnt(%0)" :: "n"(N) : "memory");
}

// ---------------------------------------------------------------------------
// Fused prep (ONE dispatch): W1 transpose+cvt, W2 transpose+cvt, X f32->bf16.
// (round-9 verified)
// ---------------------------------------------------------------------------
__global__ __launch_bounds__(256)
void prep_fused(const float* __restrict__ X,
                const float* __restrict__ W1,
                const float* __restrict__ W2,
                unsigned short* __restrict__ Xbf,
                unsigned short* __restrict__ W1t,
                unsigned short* __restrict__ W2t) {
  const int b   = blockIdx.x;
  const int tid = threadIdx.x;

  if (b >= 8192) {   // ---- X cvt ----
    const size_t i = (size_t)(b - 8192) * 256 + tid;   // 0 .. 2^21-1
    float4 v = *reinterpret_cast<const float4*>(X + i * 4);
    ushort4 o;
    o.x = f2bf(v.x); o.y = f2bf(v.y); o.z = f2bf(v.z); o.w = f2bf(v.w);
    *reinterpret_cast<ushort4*>(Xbf + i * 4) = o;
    return;
  }

  __shared__ float tile[32][33];
  const float* in;
  unsigned short* out;
  int Kd, Nd, n0, k0;
  if (b < 4096) {              // W1: Kd=1024 (H), Nd=4096 (I)
    in = W1; out = W1t; Kd = 1024; Nd = 4096;
    n0 = (b & 127) * 32;
    k0 = (b >> 7) * 32;
  } else {                     // W2: Kd=4096 (I), Nd=1024 (H)
    const int b2 = b - 4096;
    in = W2; out = W2t; Kd = 4096; Nd = 1024;
    n0 = (b2 & 31) * 32;
    k0 = (b2 >> 5) * 32;
  }
  const int tx = tid & 31;
  const int ty = tid >> 5;
#pragma unroll
  for (int i = 0; i < 4; ++i)
    tile[ty + i * 8][tx] = in[(size_t)(k0 + ty + i * 8) * Nd + n0 + tx];
  __syncthreads();
#pragma unroll
  for (int i = 0; i < 4; ++i)
    out[(size_t)(n0 + ty + i * 8) * Kd + k0 + tx] = f2bf(tile[tx][ty + i * 8]);
}

// ---------------------------------------------------------------------------
// Standalone prep kernels (fallback path only).
// ---------------------------------------------------------------------------
__global__ void cvt_f32_bf16(const float* __restrict__ in,
                             unsigned short* __restrict__ out, int n4) {
  int i = blockIdx.x * blockDim.x + threadIdx.x;
  if (i >= n4) return;
  float4 v = *reinterpret_cast<const float4*>(in + (size_t)i * 4);
  ushort4 o;
  o.x = f2bf(v.x); o.y = f2bf(v.y); o.z = f2bf(v.z); o.w = f2bf(v.w);
  *reinterpret_cast<ushort4*>(out + (size_t)i * 4) = o;
}

__global__ void transpose_cvt(const float* __restrict__ in,
                              unsigned short* __restrict__ out,
                              int Kd, int Nd) {
  __shared__ float tile[32][33];
  const int n0 = blockIdx.x * 32;
  const int k0 = blockIdx.y * 32;
  const int tx = threadIdx.x;
  const int ty = threadIdx.y;
#pragma unroll
  for (int i = 0; i < 4; ++i)
    tile[ty + i * 8][tx] = in[(size_t)(k0 + ty + i * 8) * Nd + n0 + tx];
  __syncthreads();
#pragma unroll
  for (int i = 0; i < 4; ++i)
    out[(size_t)(n0 + ty + i * 8) * Kd + k0 + tx] = f2bf(tile[tx][ty + i * 8]);
}

// ---------------------------------------------------------------------------
// QUADRANT-PHASE GEMM (round-13, passing): 256xBN tile, 8 waves, BK=64.
// Phase = C-quadrant (QM,QN) over full K=64 -> phase p needs ONLY A-half QM
// and B-half QN; halves staged 3-4 phases ahead; uniform counted waits
// {2LA, LA+LB, 2LB, LB+LA}; fragment reads at PHASE START, strictly after
// the vwait-then-barrier pair (collective completion guarantee — r14's
// pre-barrier read-ahead raced on cross-wave staging and is abandoned).
// Swizzle a^=((a>>7)&7)<<4 both sides (0-conflict); coalesced bounce
// epilogue (r12, -11us verified).
// ---------------------------------------------------------------------------
#define QPH(D, QM, QN, RDA, RDB, STAGE, WAITC)                                 \
  {                                                                            \
    if (RDA) {                                                                 \
      char* ab = lds + (D) * 32768 + (QM) * 16384;                             \
      _Pragma("unroll")                                                        \
      for (int mi = 0; mi < 4; ++mi)                                           \
        _Pragma("unroll")                                                      \
        for (int kk = 0; kk < 2; ++kk)                                         \
          aF[mi][kk] = *reinterpret_cast<const short8*>(ab + ardA[mi][kk]);    \
    }                                                                          \
    if (RDB) {                                                                 \
      char* bb = lds + 65536 + (D) * 2 * BHB + (QN) * BHB;                     \
      _Pragma("unroll")                                                        \
      for (int ni = 0; ni < NF; ++ni)                                          \
        _Pragma("unroll")                                                      \
        for (int kk = 0; kk < 2; ++kk)                                         \
          bF[QN][ni][kk] = *reinterpret_cast<const short8*>(bb + brdB[ni][kk]);\
    }                                                                          \
    STAGE;                                                                     \
    __builtin_amdgcn_s_setprio(1);                                             \
    _Pragma("unroll")                                                          \
    for (int mi = 0; mi < 4; ++mi)                                             \
      _Pragma("unroll")                                                        \
      for (int ni = 0; ni < NF; ++ni)                                          \
        _Pragma("unroll")                                                      \
        for (int kk = 0; kk < 2; ++kk)                                         \
          acc[QM][QN][mi][ni] = __builtin_amdgcn_mfma_f32_16x16x32_bf16(       \
              aF[mi][kk], bF[QN][ni][kk], acc[QM][QN][mi][ni], 0, 0, 0);       \
    __builtin_amdgcn_s_setprio(0);                                             \
    WAITC;                                                                     \
    __builtin_amdgcn_s_barrier();                                              \
  }

template <int BN, int RELU_BF16_OUT>
__global__ __launch_bounds__(512, 2)
void gemm_q(const unsigned short* __restrict__ A, int lda,
            const unsigned short* __restrict__ B, int ldb,
            const float* __restrict__ bias,
            void* __restrict__ C, int ldc, int K, int nbx) {
  constexpr int NF  = BN / 128;        // B frags per wave per quadrant (2/1)
  constexpr int LA  = 2;               // loads/thread per A-half stage
  constexpr int LB  = BN / 128;        // loads/thread per B-half stage (2/1)
  constexpr int BHB = BN * 64;         // bytes per B half-buffer (16K/8K)
  extern __shared__ char lds[];

  const int tid  = threadIdx.x;
  const int lane = tid & 63;
  const int wid  = tid >> 6;
  const int wm2  = wid >> 2;   // 0..1 (64-row slice within 128-row quadrant)
  const int wn4  = wid & 3;    // 0..3 (col slice within quadrant)

  // bijective XCD-chunked swizzle (grid % 8 == 0)
  const int cpx     = gridDim.x >> 3;
  const int logical = (blockIdx.x & 7) * cpx + (blockIdx.x >> 3);
  const int m0 = (logical / nbx) * 256;
  const int n0 = (logical % nbx) * BN;

  f32x4 acc[2][2][4][NF];
#pragma unroll
  for (int a = 0; a < 2; ++a)
#pragma unroll
    for (int b = 0; b < 2; ++b)
#pragma unroll
      for (int c = 0; c < 4; ++c)
#pragma unroll
        for (int d = 0; d < NF; ++d)
          acc[a][b][c][d] = (f32x4){0.f, 0.f, 0.f, 0.f};

  // stage maps: linear LDS dest, pre-swizzled global source.
  size_t aG[2], bG[2];
#pragma unroll
  for (int u = 0; u < 2; ++u) {
    const int s   = (u * 512 + tid) * 16;
    const int nat = s ^ (((s >> 7) & 7) << 4);
    aG[u] = (size_t)(m0 + (nat >> 7)) * lda + ((nat & 127) >> 1);
    if (u < LB)
      bG[u] = (size_t)(n0 + (nat >> 7)) * ldb + ((nat & 127) >> 1);
    else
      bG[u] = 0;
  }
  const int wb0 = (tid & 448) * 16;    // wave-uniform base (+lane*16 by HW)
  const int wb1 = 8192 + wb0;

  auto stageA = [&](int d, int h, int kel) {
    char* dst = lds + d * 32768 + h * 16384;
    gload_lds16(A + aG[0] + (size_t)h * 128 * lda + kel, dst + wb0);
    gload_lds16(A + aG[1] + (size_t)h * 128 * lda + kel, dst + wb1);
  };
  auto stageB = [&](int d, int h, int kel) {
    char* dst = lds + 65536 + d * 2 * BHB + h * BHB;
    gload_lds16(B + bG[0] + (size_t)h * (BN / 2) * ldb + kel, dst + wb0);
    if constexpr (LB == 2)
      gload_lds16(B + bG[1] + (size_t)h * (BN / 2) * ldb + kel, dst + wb1);
  };

  // swizzled ds_read offsets (within one half-buffer)
  int ardA[4][2], brdB[NF][2];
#pragma unroll
  for (int mi = 0; mi < 4; ++mi)
#pragma unroll
    for (int kk = 0; kk < 2; ++kk) {
      const int nat = (wm2 * 64 + mi * 16 + (lane & 15)) * 128 +
                      kk * 64 + (lane >> 4) * 16;
      ardA[mi][kk] = nat ^ (((nat >> 7) & 7) << 4);
    }
#pragma unroll
  for (int ni = 0; ni < NF; ++ni)
#pragma unroll
    for (int kk = 0; kk < 2; ++kk) {
      const int nat = (wn4 * (BN / 8) + ni * 16 + (lane & 15)) * 128 +
                      kk * 64 + (lane >> 4) * 16;
      brdB[ni][kk] = nat ^ (((nat >> 7) & 7) << 4);
    }

  // prologue: tile 0 halves in order [A0, B0, B1, A1]; leave B1,A1 in flight
  stageA(0, 0, 0);
  stageB(0, 0, 0);
  stageB(0, 1, 0);
  stageA(0, 1, 0);
  vwait<LA + LB>();
  __builtin_amdgcn_s_barrier();

  short8 aF[4][2];
  short8 bF[2][NF][2];
  const int NT = K >> 6;
  for (int it = 0; it < NT - 1; ++it) {
    const int d = it & 1, e = d ^ 1;
    const int nk = (it + 1) << 6;
    QPH(d, 0, 0, 1, 1, stageA(e, 0, nk), vwait<2 * LA>());
    QPH(d, 0, 1, 0, 1, stageB(e, 0, nk), (vwait<LA + LB>()));
    QPH(d, 1, 0, 1, 0, stageB(e, 1, nk), vwait<2 * LB>());
    QPH(d, 1, 1, 0, 0, stageA(e, 1, nk), (vwait<LB + LA>()));
  }
  {
    const int d = (NT - 1) & 1;
    QPH(d, 0, 0, 1, 1, ((void)0), vwait<LA>());
    QPH(d, 0, 1, 0, 1, ((void)0), vwait<0>());
    QPH(d, 1, 0, 1, 0, ((void)0), ((void)0));
    QPH(d, 1, 1, 0, 0, ((void)0), ((void)0));
  }

  // ---- Coalesced epilogue via LDS bounce (r12, verified) -----------------
  __syncthreads();
  {
#pragma unroll
    for (int qm = 0; qm < 2; ++qm) {
#pragma unroll
      for (int qn = 0; qn < 2; ++qn) {
#pragma unroll
        for (int ni = 0; ni < NF; ++ni) {
          const int c = qn * (BN / 2) + wn4 * (BN / 8) + ni * 16 + (lane & 15);
          const float bv = bias[n0 + c];
#pragma unroll
          for (int mi = 0; mi < 4; ++mi) {
#pragma unroll
            for (int rr = 0; rr < 4; ++rr) {
              const int row = qm * 128 + wm2 * 64 + mi * 16 +
                              (lane >> 4) * 4 + rr;
              float v = acc[qm][qn][mi][ni][rr] + bv;
              if (RELU_BF16_OUT) {
                v = v > 0.f ? v : 0.f;
                const int byte = (row * 512 + c * 2) ^ ((row & 7) << 4);
                *reinterpret_cast<unsigned short*>(lds + byte) = f2bf(v);
              } else {
                const int byte = (row * 512 + c * 4) ^ ((row & 7) << 4);
                *reinterpret_cast<float*>(lds + byte) = v;
              }
            }
          }
        }
      }
    }
    __syncthreads();
#pragma unroll
    for (int i = 0; i < 16; ++i) {
      const int idx  = i * 512 + tid;        // 0..8191
      const int row  = idx >> 5;
      const int g    = idx & 31;
      const int byte = (row * 512 + g * 16) ^ ((row & 7) << 4);
      const uint4 val = *reinterpret_cast<const uint4*>(lds + byte);
      if (RELU_BF16_OUT) {
        unsigned short* dst = (unsigned short*)C +
            (size_t)(m0 + row) * ldc + n0 + g * 8;
        *reinterpret_cast<uint4*>(dst) = val;
      } else {
        float* dst = (float*)C + (size_t)(m0 + row) * ldc + n0 + g * 4;
        *reinterpret_cast<uint4*>(dst) = val;
      }
    }
  }
}

// ---------------------------------------------------------------------------
// Fallback 128^2 GEMM (round-2, verified) for small-ws configurations.
// ---------------------------------------------------------------------------
template <int A_F32, int RELU_BF16_OUT>
__global__ __launch_bounds__(256, 2)
void gemm_bf16(const void* __restrict__ Ap, int lda,
               const unsigned short* __restrict__ B, int ldb,
               const float* __restrict__ bias,
               void* __restrict__ C, int ldc,
               int K, int beta) {
  __shared__ char lds[32768];
  char* const As = lds;
  char* const Bs = lds + 16384;

  const int tid  = threadIdx.x;
  const int lane = tid & 63;
  const int w    = tid >> 6;
  const int wm   = w >> 1;
  const int wn   = w & 1;
  const int m0   = blockIdx.y * 128;
  const int n0   = blockIdx.x * 128;

  f32x4 acc[4][4];
#pragma unroll
  for (int i = 0; i < 4; ++i)
#pragma unroll
    for (int j = 0; j < 4; ++j)
      acc[i][j] = (f32x4){0.f, 0.f, 0.f, 0.f};

  int srow[4], scol[4], sbase[4];
#pragma unroll
  for (int j = 0; j < 4; ++j) {
    const int stored  = (j * 256 + tid) * 16;
    const int natural = stored ^ (((stored >> 7) & 7) << 4);
    srow[j]  = natural >> 7;
    scol[j]  = (natural & 127) >> 1;
    sbase[j] = (j * 256 + (tid & 192)) * 16;
  }

  size_t agofs[4];
  int ast[4];
  if (A_F32) {
#pragma unroll
    for (int pq = 0; pq < 4; ++pq) {
      const int idx = pq * 256 + tid;
      const int rr  = idx >> 3;
      const int kbe = (idx & 7) * 8;
      agofs[pq] = (size_t)(m0 + rr) * lda + kbe;
      const int nat = rr * 128 + kbe * 2;
      ast[pq] = nat ^ (((nat >> 7) & 7) << 4);
    }
  }

  const int nsteps = K >> 6;
  for (int ks = 0; ks < nsteps; ++ks) {
    const int k0 = ks << 6;
    if (A_F32) {
      const float* Af = (const float*)Ap;
#pragma unroll
      for (int pq = 0; pq < 4; ++pq) {
        const float* sp = Af + agofs[pq] + k0;
        float4 x0 = *reinterpret_cast<const float4*>(sp);
        float4 x1 = *reinterpret_cast<const float4*>(sp + 4);
        ushort8 v;
        v[0] = f2bf(x0.x); v[1] = f2bf(x0.y); v[2] = f2bf(x0.z); v[3] = f2bf(x0.w);
        v[4] = f2bf(x1.x); v[5] = f2bf(x1.y); v[6] = f2bf(x1.z); v[7] = f2bf(x1.w);
        *reinterpret_cast<ushort8*>(As + ast[pq]) = v;
      }
    } else {
      const unsigned short* Ab = (const unsigned short*)Ap;
#pragma unroll
      for (int j = 0; j < 4; ++j)
        gload_lds16(Ab + (size_t)(m0 + srow[j]) * lda + (k0 + scol[j]),
                    As + sbase[j]);
    }
#pragma unroll
    for (int j = 0; j < 4; ++j)
      gload_lds16(B + (size_t)(n0 + srow[j]) * ldb + (k0 + scol[j]),
                  Bs + sbase[j]);
    __syncthreads();

#pragma unroll
    for (int kk = 0; kk < 2; ++kk) {
      const int kb = kk * 64 + (lane >> 4) * 16;
      short8 af[4], bfv[4];
#pragma unroll
      for (int mi = 0; mi < 4; ++mi) {
        int nat = (wm * 64 + mi * 16 + (lane & 15)) * 128 + kb;
        int st  = nat ^ (((nat >> 7) & 7) << 4);
        af[mi] = *reinterpret_cast<const short8*>(As + st);
      }
#pragma unroll
      for (int ni = 0; ni < 4; ++ni) {
        int nat = (wn * 64 + ni * 16 + (lane & 15)) * 128 + kb;
        int st  = nat ^ (((nat >> 7) & 7) << 4);
        bfv[ni] = *reinterpret_cast<const short8*>(Bs + st);
      }
#pragma unroll
      for (int mi = 0; mi < 4; ++mi)
#pragma unroll
        for (int ni = 0; ni < 4; ++ni)
          acc[mi][ni] = __builtin_amdgcn_mfma_f32_16x16x32_bf16(
              af[mi], bfv[ni], acc[mi][ni], 0, 0, 0);
    }
    __syncthreads();
  }

  const int row0 = m0 + wm * 64 + (lane >> 4) * 4;
  const int col0 = n0 + wn * 64 + (lane & 15);
#pragma unroll
  for (int ni = 0; ni < 4; ++ni) {
    const int c = col0 + ni * 16;
    const float bv = beta ? 0.f : bias[c];
#pragma unroll
    for (int mi = 0; mi < 4; ++mi) {
#pragma unroll
      for (int rr = 0; rr < 4; ++rr) {
        const size_t idx = (size_t)(row0 + mi * 16 + rr) * ldc + c;
        float v = acc[mi][ni][rr] + bv;
        if (RELU_BF16_OUT) {
          v = v > 0.f ? v : 0.f;
          ((unsigned short*)C)[idx] = f2bf(v);
        } else {
          if (beta) v += ((float*)C)[idx];
          ((float*)C)[idx] = v;
        }
      }
    }
  }
}

// ---------------------------------------------------------------------------
extern "C" void kernel_launch(void* const* d_in, const int* in_sizes, int n_in,
                              void* d_out, int out_size, void* d_ws, size_t ws_size,
                              hipStream_t stream) {
  const float* X  = (const float*)d_in[0];  // [8192][1024]
  const float* W1 = (const float*)d_in[1];  // [1024][4096]
  const float* b1 = (const float*)d_in[2];  // [4096]
  const float* W2 = (const float*)d_in[3];  // [4096][1024]
  const float* b2 = (const float*)d_in[4];  // [1024]
  float* out = (float*)d_out;               // [8192][1024] f32

  const int M = 8192, H = 1024, I = 4096;
  const size_t MB = 1024 * 1024;

  char* ws = (char*)d_ws;
  unsigned short* W1t = (unsigned short*)ws;            // [I][H] bf16, 8 MB
  unsigned short* W2t = (unsigned short*)(ws + 8 * MB); // [H][I] bf16, 8 MB

  if (ws_size >= 80 * MB) {
    // Fast path. Xbf parked in d_out tail (fully consumed by L1 before the
    // single L2 dispatch writes d_out; stream-serialized).
    unsigned short* Xbf = (unsigned short*)((char*)d_out + 16 * MB);
    unsigned short* Hbf = (unsigned short*)(ws + 16 * MB);   // [M][I] bf16
    prep_fused<<<16384, 256, 0, stream>>>(X, W1, W2, Xbf, W1t, W2t);
    // L1: Hbf = relu(X*W1+b1). quadrant-phase 256x256, grid 512, 128 KiB.
    gemm_q<256, 1><<<512, 512, 131072, stream>>>(
        Xbf, H, W1t, H, b1, Hbf, I, H, I / 256);
    // L2: out = Hbf*W2+b2. quadrant-phase 256x128, grid 256, 128 KiB.
    gemm_q<128, 0><<<256, 512, 131072, stream>>>(
        Hbf, I, W2t, I, b2, out, H, I, H / 128);
    return;
  }

  // Fallback: adaptive chunked path (round-2 verified kernels).
  transpose_cvt<<<dim3(I / 32, H / 32), dim3(32, 8), 0, stream>>>(W1, W1t, H, I);
  transpose_cvt<<<dim3(H / 32, I / 32), dim3(32, 8), 0, stream>>>(W2, W2t, I, H);

  int Ic, useXbf;
  unsigned short* Xbf = nullptr;
  unsigned short* Hc;
  if (ws_size >= 64 * MB) {
    Ic = 2048; useXbf = 1;
    Xbf = (unsigned short*)(ws + 16 * MB);
    Hc  = (unsigned short*)(ws + 32 * MB);
  } else if (ws_size >= 48 * MB) {
    Ic = 1024; useXbf = 1;
    Xbf = (unsigned short*)(ws + 16 * MB);
    Hc  = (unsigned short*)(ws + 32 * MB);
  } else if (ws_size >= 32 * MB) {
    Ic = 1024; useXbf = 0;
    Hc  = (unsigned short*)(ws + 16 * MB);
  } else if (ws_size >= 24 * MB) {
    Ic = 512;  useXbf = 0;
    Hc  = (unsigned short*)(ws + 16 * MB);
  } else if (ws_size >= 20 * MB) {
    Ic = 256;  useXbf = 0;
    Hc  = (unsigned short*)(ws + 16 * MB);
  } else {
    Ic = 128;  useXbf = 0;
    Hc  = (unsigned short*)(ws + 16 * MB);
  }

  if (useXbf) {
    int n4 = (M * H) / 4;
    cvt_f32_bf16<<<(n4 + 255) / 256, 256, 0, stream>>>(X, Xbf, n4);
  }

  const int nch = I / Ic;
  for (int c = 0; c < nch; ++c) {
    const int i0 = c * Ic;
    if (useXbf)
      gemm_bf16<0, 1><<<dim3(Ic / 128, M / 128), 256, 0, stream>>>(
          Xbf, H, W1t + (size_t)i0 * H, H, b1 + i0, Hc, Ic, H, 0);
    else
      gemm_bf16<1, 1><<<dim3(Ic / 128, M / 128), 256, 0, stream>>>(
          X, H, W1t + (size_t)i0 * H, H, b1 + i0, Hc, Ic, H, 0);
    gemm_bf16<0, 0><<<dim3(H / 128, M / 128), 256, 0, stream>>>(
        Hc, Ic, W2t + i0, I, b2, out, H, Ic, c > 0);
  }
}